// Round 1
// baseline (3351.449 us; speedup 1.0000x reference)
//
#include <hip/hip_runtime.h>

// FSU-MGU cell: exact integer reimplementation.
// T=64, B=128, I=H=1024, 2H=2048 gate cols per matrix -> 4096 combined cols.
// Gate(b,c,t) = popc(bits_b & pos_{t,c}) - popc(bits_b & neg_{t,c}) + D_{t,c}
// where pos: src>max(rp,ri), neg: src<=min(rp,ri), D = 1024 - #(src>ri) + (src_bias>rp).

#define NBLK 256
#define NTHR 512

// workspace layout (bytes); total = 77,639,680
#define WS_CNT    0u
#define WS_RNGW   256u
#define WS_RNGWI  1280u
#define WS_RNGM   2304u
#define WS_SRCB   4096u
#define WS_SRCW   12288u        // 4096*1024 u16 = 8,388,608
#define WS_XP     8400896u      // 64*128*32 u32 = 1,048,576
#define WS_HBUF   9449472u      // 2*128*32 u32 = 32,768
#define WS_DT     9482240u      // 64*4096 i32 = 1,048,576
#define WS_MASKS  10530816u     // 64*4096*64 u32 = 67,108,864

struct SRng {
  unsigned mt[3][624];
  unsigned yb[3][624];
  unsigned draws[3][1248];
  int perm[3][256];
};
struct SC {
  unsigned short rows[16][1028];  // padded stride vs bank conflicts
  int rngw[64];
  int rngwi[64];
};
struct SL {
  unsigned long long mask2[64*33]; // row stride 33 u64 (66 u32): (pos,neg) pairs
  unsigned xb[32*33];
  unsigned hb[32*33];
  int dl[64];
  int rngm[16];
};
union SU { SRng r; SC c; SL l; };

__device__ __forceinline__ unsigned mt_temper(unsigned y){
  y ^= y >> 11;
  y ^= (y << 7)  & 0x9d2c5680u;
  y ^= (y << 15) & 0xefc60000u;
  y ^= y >> 18;
  return y;
}

__device__ void mt_regen_serial(unsigned* mt){
  for (int i = 0; i < 624; i++){
    unsigned y = (mt[i] & 0x80000000u) | (mt[(i+1)%624] & 0x7fffffffu);
    mt[i] = mt[(i+397)%624] ^ (y >> 1) ^ ((y & 1u) ? 0x9908b0dfu : 0u);
  }
}

// numpy legacy RandomState: init_genrand seeding + Fisher-Yates with masked rejection.
__device__ void rng_gen(SU* sm, int* rngw, int* rngwi, int* rngm){
  const int tid = threadIdx.x;
  const int wv = tid >> 6, lane = tid & 63;
  const bool act = (wv < 3);
  if (act && lane == 0){
    unsigned* mt = sm->r.mt[wv];
    mt[0] = (unsigned)wv;  // seeds 0,1,2
    for (int i = 1; i < 624; i++)
      mt[i] = 1812433253u * (mt[i-1] ^ (mt[i-1] >> 30)) + (unsigned)i;
  }
  __syncthreads();
  for (int r = 0; r < 2; r++){
    if (act){
      unsigned* mt = sm->r.mt[wv]; unsigned* yb = sm->r.yb[wv];
      for (int i = lane; i < 623; i += 64)
        yb[i] = (mt[i] & 0x80000000u) | (mt[i+1] & 0x7fffffffu);
    }
    __syncthreads();
    if (act){
      unsigned* mt = sm->r.mt[wv]; unsigned* yb = sm->r.yb[wv];
      for (int i = lane; i < 227; i += 64){
        unsigned y = yb[i];
        mt[i] = mt[i+397] ^ (y >> 1) ^ ((y & 1u) ? 0x9908b0dfu : 0u);
      }
    }
    __syncthreads();
    if (act){
      unsigned* mt = sm->r.mt[wv]; unsigned* yb = sm->r.yb[wv];
      for (int i = 227 + lane; i < 454; i += 64){
        unsigned y = yb[i];
        mt[i] = mt[i-227] ^ (y >> 1) ^ ((y & 1u) ? 0x9908b0dfu : 0u);
      }
    }
    __syncthreads();
    if (act){
      unsigned* mt = sm->r.mt[wv]; unsigned* yb = sm->r.yb[wv];
      for (int i = 454 + lane; i < 624; i += 64){
        unsigned y = (i < 623) ? yb[i]
                   : ((mt[623] & 0x80000000u) | (mt[0] & 0x7fffffffu));
        mt[i] = mt[i-227] ^ (y >> 1) ^ ((y & 1u) ? 0x9908b0dfu : 0u);
      }
    }
    __syncthreads();
    if (act){
      unsigned* mt = sm->r.mt[wv];
      for (int i = lane; i < 624; i += 64)
        sm->r.draws[wv][r*624 + i] = mt_temper(mt[i]);
    }
    __syncthreads();
  }
  if (act && lane == 0){
    const int n = (wv == 2) ? 16 : 256;
    int* perm = sm->r.perm[wv];
    for (int i = 0; i < n; i++) perm[i] = i;
    int dp = 0, spos = 624;
    unsigned* mt = sm->r.mt[wv];
    for (int i = n - 1; i > 0; i--){
      unsigned mask = (unsigned)i;
      mask |= mask >> 1; mask |= mask >> 2; mask |= mask >> 4;
      mask |= mask >> 8; mask |= mask >> 16;
      unsigned v;
      do {
        unsigned d;
        if (dp < 1248) d = sm->r.draws[wv][dp++];
        else {
          if (spos >= 624){ mt_regen_serial(mt); spos = 0; }
          d = mt_temper(mt[spos++]);
        }
        v = d & mask;
      } while (v > (unsigned)i);
      int tmp = perm[i]; perm[i] = perm[v]; perm[v] = tmp;
    }
    int* dst = (wv == 0) ? rngw : (wv == 1) ? rngwi : rngm;
    for (int i = 0; i < n; i++) dst[i] = perm[i];
  }
}

__device__ __forceinline__ void gbar(unsigned* cnt, unsigned ep){
  __syncthreads();
  if (threadIdx.x == 0){
    __threadfence();
    atomicAdd(cnt, 1u);
    const unsigned tgt = ep * (unsigned)NBLK;
    while (__hip_atomic_load(cnt, __ATOMIC_RELAXED, __HIP_MEMORY_SCOPE_AGENT) < tgt)
      __builtin_amdgcn_s_sleep(2);
  }
  __syncthreads();
  __threadfence();
}

__device__ __forceinline__ int clampi(int v){
  v = v < -512 ? -512 : v;
  v = v >  512 ?  512 : v;
  return v;
}

__global__ void __launch_bounds__(NTHR)
fsu_kernel(const float* __restrict__ x, const float* __restrict__ hx0,
           const float* __restrict__ wih, const float* __restrict__ bih,
           const float* __restrict__ whh, const float* __restrict__ bhh,
           float* __restrict__ out, unsigned char* __restrict__ ws)
{
  __shared__ SU sm;
  const int tid = threadIdx.x;
  const int bid = blockIdx.x;

  unsigned* cnt = (unsigned*)(ws + WS_CNT);
  int* rngw  = (int*)(ws + WS_RNGW);
  int* rngwi = (int*)(ws + WS_RNGWI);
  int* rngm  = (int*)(ws + WS_RNGM);
  unsigned short* srcb = (unsigned short*)(ws + WS_SRCB);
  unsigned short* srcw = (unsigned short*)(ws + WS_SRCW);
  unsigned* xp   = (unsigned*)(ws + WS_XP);
  unsigned* hbuf = (unsigned*)(ws + WS_HBUF);
  int* Dt = (int*)(ws + WS_DT);
  unsigned long long* masks = (unsigned long long*)(ws + WS_MASKS);

  // ---------- phase 0: RNG tables (block 0) || bit-pack + src build (others)
  if (bid == 0){
    rng_gen(&sm, rngw, rngwi, rngm);
  } else {
    const int gtid = (bid - 1)*NTHR + tid;
    const int lane = tid & 63;
    const int gw = gtid >> 6;
    const int nw = (NBLK-1)*(NTHR/64);
    const int nthr = (NBLK-1)*NTHR;
    for (int ch = gw; ch < 131072; ch += nw){            // x bits
      float v = x[(size_t)ch*64 + lane];
      unsigned long long bal = __ballot(v != 0.0f);
      if ((lane & 31) == 0) xp[ch*2 + (lane >> 5)] = (unsigned)(bal >> lane);
    }
    for (int ch = gw; ch < 2048; ch += nw){              // hx0 bits -> parity 0
      float v = hx0[(size_t)ch*64 + lane];
      unsigned long long bal = __ballot(v != 0.0f);
      if ((lane & 31) == 0) hbuf[ch*2 + (lane >> 5)] = (unsigned)(bal >> lane);
    }
    for (int idx = gtid; idx < 4096*1024; idx += nthr){  // src = round((clip+1)*128)
      int c = idx >> 10, k = idx & 1023;
      float wv2 = (c < 2048) ? wih[(size_t)c*1024 + k] : whh[(size_t)(c - 2048)*1024 + k];
      float cl = fminf(fmaxf(wv2, -1.0f), 1.0f);
      srcw[idx] = (unsigned short)(int)rintf((cl + 1.0f)*0.5f*256.0f);
    }
    for (int c = gtid; c < 4096; c += nthr){
      float bv = (c < 2048) ? bih[c] : bhh[c - 2048];
      float cl = fminf(fmaxf(bv, -1.0f), 1.0f);
      srcb[c] = (unsigned short)(int)rintf((cl + 1.0f)*0.5f*256.0f);
    }
  }
  gbar(cnt, 1u);

  // ---------- phase C: pos/neg masks + D constants for all (t, col)
  {
    const int c0 = bid * 16;
    const unsigned* srcw32 = (const unsigned*)srcw;
    for (int q = tid; q < 16*512; q += NTHR){
      int r = q >> 9, w = q & 511;
      ((unsigned*)&sm.c.rows[r][0])[w] = srcw32[(size_t)(c0 + r)*512 + w];
    }
    if (tid < 64) sm.c.rngw[tid] = rngw[tid];
    if (tid >= 64 && tid < 128) sm.c.rngwi[tid - 64] = rngwi[tid - 64];
    __syncthreads();
    for (int rr = 0; rr < 2; rr++){
      int row = tid + rr*NTHR;            // 0..1023 : (t, local col)
      int t = row >> 4, lc = row & 15, col = c0 + lc;
      int rp = sm.c.rngw[t], ri = sm.c.rngwi[t];
      int hi = rp > ri ? rp : ri;
      int lo1 = (rp < ri ? rp : ri) + 1;
      bool rihi = (ri >= rp);
      const unsigned* srow = (const unsigned*)&sm.c.rows[lc][0];
      unsigned long long* gdst = masks + ((size_t)t*4096 + col)*32;
      int cnti = 0;
      for (int w = 0; w < 32; w++){
        unsigned pos = 0, neg = 0;
        #pragma unroll
        for (int i2 = 15; i2 >= 0; i2--){
          unsigned v2 = srow[w*16 + i2];
          int vH = (int)(v2 >> 16);
          int vL = (int)(v2 & 0xFFFFu);
          pos = (pos << 1) | ((unsigned)(hi - vH) >> 31);   // v > hi
          neg = (neg << 1) | ((unsigned)(vH - lo1) >> 31);  // v <= lo
          pos = (pos << 1) | ((unsigned)(hi - vL) >> 31);
          neg = (neg << 1) | ((unsigned)(vL - lo1) >> 31);
        }
        gdst[w] = (unsigned long long)pos | ((unsigned long long)neg << 32);
        cnti += rihi ? __popc(pos) : (32 - __popc(neg));    // count(src > ri)
      }
      Dt[t*4096 + col] = 1024 - cnti + (((int)srcb[col] > rp) ? 1 : 0);
    }
  }
  gbar(cnt, 2u);

  // ---------- main recurrence
  const int jt = bid >> 2, bg = bid & 3;
  const int j0 = jt * 16, b0 = bg * 32;
  const int b_l = tid >> 4, j_l = tid & 15;
  const int bglob = b0 + b_l;

  int hcur = (hx0[(size_t)bglob*1024 + j0 + j_l] != 0.0f) ? 1 : 0;
  int A1=0,A2=0,A3=0,A4=0,A5=0,A6=0;          // 2x-scaled accumulators
  unsigned sr1=10u, sr2=10u, sr3=10u;          // shift regs, init [0,1,0,1] -> 0b1010
  int i1p=0,i1i=0,i2p=0,i2i=0,i3p=0,i3i=0;

  if (tid < 16) sm.l.rngm[tid] = rngm[tid];

  for (int t = 0; t < 64; t++){
    const int par = t & 1;
    const unsigned* msrc = (const unsigned*)masks;
    unsigned* mlds = (unsigned*)sm.l.mask2;
    for (int q = tid; q < 4096; q += NTHR){
      int r = q >> 6, qq = q & 63;
      int c = (r >> 4)*1024 + j0 + (r & 15);
      mlds[r*66 + qq] = msrc[((size_t)t*4096 + c)*64 + qq];
    }
    for (int q = tid; q < 1024; q += NTHR){
      int bb = q >> 5, w = q & 31;
      sm.l.xb[bb*33 + w] = xp[((size_t)t*128 + b0 + bb)*32 + w];
      sm.l.hb[bb*33 + w] = hbuf[(size_t)par*4096 + (size_t)(b0 + bb)*32 + w];
    }
    if (tid < 64){
      int c = (tid >> 4)*1024 + j0 + (tid & 15);
      sm.l.dl[tid] = Dt[t*4096 + c];
    }
    __syncthreads();

    int p0=0,n0=0,p1=0,n1=0,p2=0,n2=0,p3=0,n3=0;
    const unsigned long long* m0r = &sm.l.mask2[(0*16 + j_l)*33];
    const unsigned long long* m1r = &sm.l.mask2[(1*16 + j_l)*33];
    const unsigned long long* m2r = &sm.l.mask2[(2*16 + j_l)*33];
    const unsigned long long* m3r = &sm.l.mask2[(3*16 + j_l)*33];
    const unsigned* xrow = &sm.l.xb[b_l*33];
    const unsigned* hrow = &sm.l.hb[b_l*33];
    #pragma unroll 8
    for (int w = 0; w < 32; w++){
      unsigned xw = xrow[w], hw = hrow[w];
      unsigned long long a = m0r[w];
      p0 += __popc(xw & (unsigned)a); n0 += __popc(xw & (unsigned)(a >> 32));
      unsigned long long b = m1r[w];
      p1 += __popc(xw & (unsigned)b); n1 += __popc(xw & (unsigned)(b >> 32));
      unsigned long long c2 = m2r[w];
      p2 += __popc(hw & (unsigned)c2); n2 += __popc(hw & (unsigned)(c2 >> 32));
      unsigned long long d = m3r[w];
      p3 += __popc(hw & (unsigned)d); n3 += __popc(hw & (unsigned)(d >> 32));
    }
    const int g_if = sm.l.dl[0*16 + j_l] + p0 - n0;
    const int g_in = sm.l.dl[1*16 + j_l] + p1 - n1;
    const int g_hf = sm.l.dl[2*16 + j_l] + p2 - n2;
    const int g_hn = sm.l.dl[3*16 + j_l] + p3 - n3;

    // ---- FSU elementwise chain (exact, 2x-scaled ints)
    int s1 = g_if + g_hf;
    A1 = clampi(A1 + 2*s1 - 2049);                 // off_fg = 1024.5
    int fg_in = (A1 >= 2); A1 -= fg_in << 1;
    A2 = clampi(A2 + ((fg_in + 1) << 1));          // off 0, scale 2
    int fg = (A2 >= 4); A2 -= fg << 2;
    A3 = clampi(A3 + (g_hn << 1) - 1024);          // off 512
    int hnb = (A3 >= 2); A3 -= hnb << 1;

    sr1 = ((sr1 >> 1) | ((unsigned)hnb << 3)) & 0xFu;
    int ng_prod;
    {
      int cv = __popc(sr1) << 2;
      int bp = cv > sm.l.rngm[i1p & 15];
      int bi = cv > sm.l.rngm[i1i & 15];
      ng_prod = fg ? bp : (1 - bi);
      i1p += fg; i1i += 1 - fg;
    }
    A4 = clampi(A4 + (g_in << 1) - 1024);          // off 512
    int inb = (A4 >= 2); A4 -= inb << 1;
    A5 = clampi(A5 + ((inb + ng_prod) << 1) - 1);  // off 0.5
    int ng = (A5 >= 2); A5 -= ng << 1;

    sr2 = ((sr2 >> 1) | ((unsigned)ng << 3)) & 0xFu;
    int fgi;
    {
      int cv = __popc(sr2) << 2;
      int bp = cv > sm.l.rngm[i2p & 15];
      int bi = cv > sm.l.rngm[i2i & 15];
      fgi = (1 - fg) ? bp : (1 - bi);              // in0 = 1-fg
      i2p += 1 - fg; i2i += fg;
    }
    sr3 = ((sr3 >> 1) | ((unsigned)hcur << 3)) & 0xFu;
    int fgp;
    {
      int cv = __popc(sr3) << 2;
      int bp = cv > sm.l.rngm[i3p & 15];
      int bi = cv > sm.l.rngm[i3i & 15];
      fgp = fg ? bp : (1 - bi);                    // in0 = fg
      i3p += fg; i3i += 1 - fg;
    }
    A6 = clampi(A6 + ((ng + fgi + fgp) << 1) - 2); // off 1.0
    int hy = (A6 >= 2); A6 -= hy << 1;

    out[(size_t)t*131072 + (size_t)bglob*1024 + j0 + j_l] = (float)hy;

    unsigned long long bal = __ballot(hy);
    if ((tid & 15) == 0){
      unsigned short v16 = (unsigned short)(bal >> (((tid >> 4) & 3)*16));
      ((unsigned short*)hbuf)[((size_t)(par ^ 1)*128 + bglob)*64 + jt] = v16;
    }
    hcur = hy;
    gbar(cnt, (unsigned)(3 + t));
  }
}

extern "C" void kernel_launch(void* const* d_in, const int* in_sizes, int n_in,
                              void* d_out, int out_size, void* d_ws, size_t ws_size,
                              hipStream_t stream)
{
  (void)in_sizes; (void)n_in; (void)out_size; (void)ws_size;
  const float* x   = (const float*)d_in[0];
  const float* hx0 = (const float*)d_in[1];
  const float* wih = (const float*)d_in[2];
  const float* bih = (const float*)d_in[3];
  const float* whh = (const float*)d_in[4];
  const float* bhh = (const float*)d_in[5];
  float* out = (float*)d_out;
  unsigned char* ws = (unsigned char*)d_ws;

  // reset barrier counter every call (graph-replay safe)
  hipMemsetAsync(d_ws, 0, 256, stream);

  void* args[] = { (void*)&x, (void*)&hx0, (void*)&wih, (void*)&bih,
                   (void*)&whh, (void*)&bhh, (void*)&out, (void*)&ws };
  hipLaunchCooperativeKernel(reinterpret_cast<void*>(fsu_kernel),
                             dim3(NBLK), dim3(NTHR), args, 0, stream);
}

// Round 2
// 2793.540 us; speedup vs baseline: 1.1997x; 1.1997x over previous
//
#include <hip/hip_runtime.h>

// FSU-MGU cell: exact integer reimplementation.
// Gate(b,c,t) = popc(bits_b & pos_{t,c}) - popc(bits_b & neg_{t,c}) + D_{t,c}
// pos: src>max(rp,ri), neg: src<=min(rp,ri), D = 1024 - #(src>ri) + (src_bias>rp).

#define NBLK 256
#define NTHR 512

// workspace layout (bytes)
// barrier area [0, 8192) -- zeroed by hipMemsetAsync each call
#define WS_BAR_SUB   0u        // 8 counter lines, stride 128
#define WS_BAR_MST   1024u     // master counter
#define WS_BAR_FLG   2048u     // 8 flag lines, stride 128
#define WS_BGC       3072u     // 4 per-bg counter lines
#define WS_BGF       3584u     // 16 per-bg flag lines (4 bg x 4 replicas)
#define WS_RNGW   8192u
#define WS_RNGWI  9216u
#define WS_RNGM   10240u
#define WS_SRCB   12288u       // 4096 u16
#define WS_SRCW   20480u       // 4096*1024 u16 = 8,388,608
#define WS_XP     8409088u     // 64*128*32 u32 = 1,048,576
#define WS_HBUF   9457664u     // 2*128*32 u32 = 32,768
#define WS_DT     9490432u     // 64*4096 i32 = 1,048,576
#define WS_MASKS  10539008u    // 64*4096*64 u32 = 67,108,864  (end 77,647,872)

struct SRng {
  unsigned mt[3][624];
  unsigned yb[3][624];
  unsigned draws[3][1248];
  int perm[3][256];
};
struct SC {
  unsigned short rows[16][1028];
  int rngw[64];
  int rngwi[64];
};
struct SL {
  unsigned long long mask2[64*33]; // row stride 33 u64
  unsigned xb[32*33];
  unsigned hb[32*33];
  int dl[64];
  int rngm[16];
};
union SU { SRng r; SC c; SL l; };

__device__ __forceinline__ unsigned mt_temper(unsigned y){
  y ^= y >> 11;
  y ^= (y << 7)  & 0x9d2c5680u;
  y ^= (y << 15) & 0xefc60000u;
  y ^= y >> 18;
  return y;
}

__device__ void mt_regen_serial(unsigned* mt){
  for (int i = 0; i < 624; i++){
    unsigned y = (mt[i] & 0x80000000u) | (mt[(i+1)%624] & 0x7fffffffu);
    mt[i] = mt[(i+397)%624] ^ (y >> 1) ^ ((y & 1u) ? 0x9908b0dfu : 0u);
  }
}

// numpy legacy RandomState: init_genrand seeding + Fisher-Yates with masked rejection.
__device__ void rng_gen(SU* sm, int* rngw, int* rngwi, int* rngm){
  const int tid = threadIdx.x;
  const int wv = tid >> 6, lane = tid & 63;
  const bool act = (wv < 3);
  if (act && lane == 0){
    unsigned* mt = sm->r.mt[wv];
    mt[0] = (unsigned)wv;  // seeds 0,1,2
    for (int i = 1; i < 624; i++)
      mt[i] = 1812433253u * (mt[i-1] ^ (mt[i-1] >> 30)) + (unsigned)i;
  }
  __syncthreads();
  for (int r = 0; r < 2; r++){
    if (act){
      unsigned* mt = sm->r.mt[wv]; unsigned* yb = sm->r.yb[wv];
      for (int i = lane; i < 623; i += 64)
        yb[i] = (mt[i] & 0x80000000u) | (mt[i+1] & 0x7fffffffu);
    }
    __syncthreads();
    if (act){
      unsigned* mt = sm->r.mt[wv]; unsigned* yb = sm->r.yb[wv];
      for (int i = lane; i < 227; i += 64){
        unsigned y = yb[i];
        mt[i] = mt[i+397] ^ (y >> 1) ^ ((y & 1u) ? 0x9908b0dfu : 0u);
      }
    }
    __syncthreads();
    if (act){
      unsigned* mt = sm->r.mt[wv]; unsigned* yb = sm->r.yb[wv];
      for (int i = 227 + lane; i < 454; i += 64){
        unsigned y = yb[i];
        mt[i] = mt[i-227] ^ (y >> 1) ^ ((y & 1u) ? 0x9908b0dfu : 0u);
      }
    }
    __syncthreads();
    if (act){
      unsigned* mt = sm->r.mt[wv]; unsigned* yb = sm->r.yb[wv];
      for (int i = 454 + lane; i < 624; i += 64){
        unsigned y = (i < 623) ? yb[i]
                   : ((mt[623] & 0x80000000u) | (mt[0] & 0x7fffffffu));
        mt[i] = mt[i-227] ^ (y >> 1) ^ ((y & 1u) ? 0x9908b0dfu : 0u);
      }
    }
    __syncthreads();
    if (act){
      unsigned* mt = sm->r.mt[wv];
      for (int i = lane; i < 624; i += 64)
        sm->r.draws[wv][r*624 + i] = mt_temper(mt[i]);
    }
    __syncthreads();
  }
  if (act && lane == 0){
    const int n = (wv == 2) ? 16 : 256;
    int* perm = sm->r.perm[wv];
    for (int i = 0; i < n; i++) perm[i] = i;
    int dp = 0, spos = 624;
    unsigned* mt = sm->r.mt[wv];
    for (int i = n - 1; i > 0; i--){
      unsigned mask = (unsigned)i;
      mask |= mask >> 1; mask |= mask >> 2; mask |= mask >> 4;
      mask |= mask >> 8; mask |= mask >> 16;
      unsigned v;
      do {
        unsigned d;
        if (dp < 1248) d = sm->r.draws[wv][dp++];
        else {
          if (spos >= 624){ mt_regen_serial(mt); spos = 0; }
          d = mt_temper(mt[spos++]);
        }
        v = d & mask;
      } while (v > (unsigned)i);
      int tmp = perm[i]; perm[i] = perm[v]; perm[v] = tmp;
    }
    int* dst = (wv == 0) ? rngw : (wv == 1) ? rngwi : rngm;
    for (int i = 0; i < n; i++) dst[i] = perm[i];
  }
}

// full-grid barrier: 2-level arrival counters + replicated release flags
__device__ __forceinline__ void gbar_full(unsigned char* ws, unsigned ep){
  __syncthreads();
  if (threadIdx.x == 0){
    __threadfence();
    unsigned* sub = (unsigned*)(ws + WS_BAR_SUB + (blockIdx.x & 7)*128);
    unsigned old = atomicAdd(sub, 1u);
    if (old == ep*32u - 1u){
      unsigned* mst = (unsigned*)(ws + WS_BAR_MST);
      unsigned mo = atomicAdd(mst, 1u);
      if (mo == ep*8u - 1u){
        for (int i = 0; i < 8; i++)
          __hip_atomic_store((unsigned*)(ws + WS_BAR_FLG + i*128), ep,
                             __ATOMIC_RELAXED, __HIP_MEMORY_SCOPE_AGENT);
      }
    }
    const unsigned* fl = (const unsigned*)(ws + WS_BAR_FLG + (blockIdx.x & 7)*128);
    while (__hip_atomic_load(fl, __ATOMIC_RELAXED, __HIP_MEMORY_SCOPE_AGENT) < ep)
      __builtin_amdgcn_s_sleep(8);
  }
  __syncthreads();
  __threadfence();
}

// per-b-group barrier: 64 arrivals, 4 flag replicas
__device__ __forceinline__ void gbar_bg(unsigned char* ws, int bg, int rep, unsigned ep){
  __syncthreads();
  if (threadIdx.x == 0){
    __threadfence();
    unsigned* cb = (unsigned*)(ws + WS_BGC + bg*128);
    unsigned old = atomicAdd(cb, 1u);
    if (old == ep*64u - 1u){
      for (int i = 0; i < 4; i++)
        __hip_atomic_store((unsigned*)(ws + WS_BGF + (bg*4 + i)*128), ep,
                           __ATOMIC_RELAXED, __HIP_MEMORY_SCOPE_AGENT);
    }
    const unsigned* fl = (const unsigned*)(ws + WS_BGF + (bg*4 + rep)*128);
    while (__hip_atomic_load(fl, __ATOMIC_RELAXED, __HIP_MEMORY_SCOPE_AGENT) < ep)
      __builtin_amdgcn_s_sleep(8);
  }
  __syncthreads();
  __threadfence();
}

__device__ __forceinline__ int clampi(int v){
  v = v < -512 ? -512 : v;
  v = v >  512 ?  512 : v;
  return v;
}

__global__ void __launch_bounds__(NTHR)
fsu_kernel(const float* __restrict__ x, const float* __restrict__ hx0,
           const float* __restrict__ wih, const float* __restrict__ bih,
           const float* __restrict__ whh, const float* __restrict__ bhh,
           float* __restrict__ out, unsigned char* __restrict__ ws)
{
  __shared__ SU sm;
  const int tid = threadIdx.x;
  const int bid = blockIdx.x;

  int* rngw  = (int*)(ws + WS_RNGW);
  int* rngwi = (int*)(ws + WS_RNGWI);
  int* rngm  = (int*)(ws + WS_RNGM);
  unsigned short* srcb = (unsigned short*)(ws + WS_SRCB);
  unsigned short* srcw = (unsigned short*)(ws + WS_SRCW);
  unsigned* xp   = (unsigned*)(ws + WS_XP);
  unsigned* hbuf = (unsigned*)(ws + WS_HBUF);
  int* Dt = (int*)(ws + WS_DT);
  unsigned long long* masks = (unsigned long long*)(ws + WS_MASKS);

  // ---------- phase 0: RNG tables (block 0) || bit-pack + src build (others)
  if (bid == 0){
    rng_gen(&sm, rngw, rngwi, rngm);
  } else {
    const int gtid = (bid - 1)*NTHR + tid;
    const int lane = tid & 63;
    const int gw = gtid >> 6;
    const int nw = (NBLK-1)*(NTHR/64);
    const int nthr = (NBLK-1)*NTHR;
    for (int ch = gw; ch < 131072; ch += nw){            // x bits
      float v = x[(size_t)ch*64 + lane];
      unsigned long long bal = __ballot(v != 0.0f);
      if ((lane & 31) == 0) xp[ch*2 + (lane >> 5)] = (unsigned)(bal >> lane);
    }
    for (int ch = gw; ch < 2048; ch += nw){              // hx0 bits -> parity 0
      float v = hx0[(size_t)ch*64 + lane];
      unsigned long long bal = __ballot(v != 0.0f);
      if ((lane & 31) == 0) hbuf[ch*2 + (lane >> 5)] = (unsigned)(bal >> lane);
    }
    for (int idx = gtid; idx < 4096*1024; idx += nthr){  // src = round((clip+1)*128)
      int c = idx >> 10, k = idx & 1023;
      float wv2 = (c < 2048) ? wih[(size_t)c*1024 + k] : whh[(size_t)(c - 2048)*1024 + k];
      float cl = fminf(fmaxf(wv2, -1.0f), 1.0f);
      srcw[idx] = (unsigned short)(int)rintf((cl + 1.0f)*0.5f*256.0f);
    }
    for (int c = gtid; c < 4096; c += nthr){
      float bv = (c < 2048) ? bih[c] : bhh[c - 2048];
      float cl = fminf(fmaxf(bv, -1.0f), 1.0f);
      srcb[c] = (unsigned short)(int)rintf((cl + 1.0f)*0.5f*256.0f);
    }
  }
  gbar_full(ws, 1u);

  // ---------- phase C: pos/neg masks + D constants for all (t, col)
  {
    const int c0 = bid * 16;
    const unsigned* srcw32 = (const unsigned*)srcw;
    for (int q = tid; q < 16*512; q += NTHR){
      int r = q >> 9, w = q & 511;
      ((unsigned*)&sm.c.rows[r][0])[w] = srcw32[(size_t)(c0 + r)*512 + w];
    }
    if (tid < 64) sm.c.rngw[tid] = rngw[tid];
    if (tid >= 64 && tid < 128) sm.c.rngwi[tid - 64] = rngwi[tid - 64];
    __syncthreads();
    for (int rr = 0; rr < 2; rr++){
      int row = tid + rr*NTHR;            // 0..1023 : (t, local col)
      int t = row >> 4, lc = row & 15, col = c0 + lc;
      int rp = sm.c.rngw[t], ri = sm.c.rngwi[t];
      int hi = rp > ri ? rp : ri;
      int lo1 = (rp < ri ? rp : ri) + 1;
      bool rihi = (ri >= rp);
      const unsigned* srow = (const unsigned*)&sm.c.rows[lc][0];
      unsigned long long* gdst = masks + ((size_t)t*4096 + col)*32;
      int cnti = 0;
      for (int w = 0; w < 32; w++){
        unsigned pos = 0, neg = 0;
        #pragma unroll
        for (int i2 = 15; i2 >= 0; i2--){
          unsigned v2 = srow[w*16 + i2];
          int vH = (int)(v2 >> 16);
          int vL = (int)(v2 & 0xFFFFu);
          pos = (pos << 1) | ((unsigned)(hi - vH) >> 31);   // v > hi
          neg = (neg << 1) | ((unsigned)(vH - lo1) >> 31);  // v <= lo
          pos = (pos << 1) | ((unsigned)(hi - vL) >> 31);
          neg = (neg << 1) | ((unsigned)(vL - lo1) >> 31);
        }
        gdst[w] = (unsigned long long)pos | ((unsigned long long)neg << 32);
        cnti += rihi ? __popc(pos) : (32 - __popc(neg));    // count(src > ri)
      }
      Dt[t*4096 + col] = 1024 - cnti + (((int)srcb[col] > rp) ? 1 : 0);
    }
  }
  gbar_full(ws, 2u);

  // ---------- main recurrence
  const int jt = bid >> 2, bg = bid & 3;
  const int rep = jt & 3;
  const int j0 = jt * 16, b0 = bg * 32;
  const int b_l = tid >> 4, j_l = tid & 15;
  const int bglob = b0 + b_l;

  int hcur = (hx0[(size_t)bglob*1024 + j0 + j_l] != 0.0f) ? 1 : 0;
  int A1=0,A2=0,A3=0,A4=0,A5=0,A6=0;          // 2x-scaled accumulators
  unsigned sr1=10u, sr2=10u, sr3=10u;          // shift regs, init [0,1,0,1]
  int i1p=0,i1i=0,i2p=0,i2i=0,i3p=0,i3i=0;

  if (tid < 16) sm.l.rngm[tid] = rngm[tid];

  const unsigned* msrc = (const unsigned*)masks;
  unsigned* mlds = (unsigned*)sm.l.mask2;

  // prime stage for t=0 (direct global -> LDS)
  {
    #pragma unroll
    for (int i = 0; i < 8; i++){
      int q = tid + i*NTHR;
      int r = q >> 6, qq = q & 63;
      int c = (r >> 4)*1024 + j0 + (r & 15);
      mlds[r*66 + qq] = msrc[((size_t)0*4096 + c)*64 + qq];
    }
    #pragma unroll
    for (int i = 0; i < 2; i++){
      int q = tid + i*NTHR;
      int bb = q >> 5, w = q & 31;
      sm.l.xb[bb*33 + w] = xp[((size_t)0*128 + b0 + bb)*32 + w];
      sm.l.hb[bb*33 + w] = hbuf[(size_t)(b0 + bb)*32 + w];
    }
    if (tid < 64){
      int c = (tid >> 4)*1024 + j0 + (tid & 15);
      sm.l.dl[tid] = Dt[0*4096 + c];
    }
    __syncthreads();
  }

  for (int t = 0; t < 64; t++){
    const int par = t & 1;

    int p0=0,n0=0,p1=0,n1=0,p2=0,n2=0,p3=0,n3=0;
    const unsigned long long* m0r = &sm.l.mask2[(0*16 + j_l)*33];
    const unsigned long long* m1r = &sm.l.mask2[(1*16 + j_l)*33];
    const unsigned long long* m2r = &sm.l.mask2[(2*16 + j_l)*33];
    const unsigned long long* m3r = &sm.l.mask2[(3*16 + j_l)*33];
    const unsigned* xrow = &sm.l.xb[b_l*33];
    const unsigned* hrow = &sm.l.hb[b_l*33];
    #pragma unroll 8
    for (int w = 0; w < 32; w++){
      unsigned xw = xrow[w], hw = hrow[w];
      unsigned long long a = m0r[w];
      p0 += __popc(xw & (unsigned)a); n0 += __popc(xw & (unsigned)(a >> 32));
      unsigned long long b = m1r[w];
      p1 += __popc(xw & (unsigned)b); n1 += __popc(xw & (unsigned)(b >> 32));
      unsigned long long c2 = m2r[w];
      p2 += __popc(hw & (unsigned)c2); n2 += __popc(hw & (unsigned)(c2 >> 32));
      unsigned long long d = m3r[w];
      p3 += __popc(hw & (unsigned)d); n3 += __popc(hw & (unsigned)(d >> 32));
    }
    const int g_if = sm.l.dl[0*16 + j_l] + p0 - n0;
    const int g_in = sm.l.dl[1*16 + j_l] + p1 - n1;
    const int g_hf = sm.l.dl[2*16 + j_l] + p2 - n2;
    const int g_hn = sm.l.dl[3*16 + j_l] + p3 - n3;

    // ---- FSU elementwise chain (exact, 2x-scaled ints)
    int s1 = g_if + g_hf;
    A1 = clampi(A1 + 2*s1 - 2049);                 // off_fg = 1024.5
    int fg_in = (A1 >= 2); A1 -= fg_in << 1;
    A2 = clampi(A2 + ((fg_in + 1) << 1));          // off 0, scale 2
    int fg = (A2 >= 4); A2 -= fg << 2;
    A3 = clampi(A3 + (g_hn << 1) - 1024);          // off 512
    int hnb = (A3 >= 2); A3 -= hnb << 1;

    sr1 = ((sr1 >> 1) | ((unsigned)hnb << 3)) & 0xFu;
    int ng_prod;
    {
      int cv = __popc(sr1) << 2;
      int bp = cv > sm.l.rngm[i1p & 15];
      int bi = cv > sm.l.rngm[i1i & 15];
      ng_prod = fg ? bp : (1 - bi);
      i1p += fg; i1i += 1 - fg;
    }
    A4 = clampi(A4 + (g_in << 1) - 1024);          // off 512
    int inb = (A4 >= 2); A4 -= inb << 1;
    A5 = clampi(A5 + ((inb + ng_prod) << 1) - 1);  // off 0.5
    int ng = (A5 >= 2); A5 -= ng << 1;

    sr2 = ((sr2 >> 1) | ((unsigned)ng << 3)) & 0xFu;
    int fgi;
    {
      int cv = __popc(sr2) << 2;
      int bp = cv > sm.l.rngm[i2p & 15];
      int bi = cv > sm.l.rngm[i2i & 15];
      fgi = (1 - fg) ? bp : (1 - bi);              // in0 = 1-fg
      i2p += 1 - fg; i2i += fg;
    }
    sr3 = ((sr3 >> 1) | ((unsigned)hcur << 3)) & 0xFu;
    int fgp;
    {
      int cv = __popc(sr3) << 2;
      int bp = cv > sm.l.rngm[i3p & 15];
      int bi = cv > sm.l.rngm[i3i & 15];
      fgp = fg ? bp : (1 - bi);                    // in0 = fg
      i3p += fg; i3i += 1 - fg;
    }
    A6 = clampi(A6 + ((ng + fgi + fgp) << 1) - 2); // off 1.0
    int hy = (A6 >= 2); A6 -= hy << 1;

    out[(size_t)t*131072 + (size_t)bglob*1024 + j0 + j_l] = (float)hy;
    hcur = hy;

    if (t < 63){
      // exchange h bits for step t+1 (parity par^1)
      unsigned long long bal = __ballot(hy);
      if ((tid & 15) == 0){
        unsigned short v16 = (unsigned short)(bal >> (((tid >> 4) & 3)*16));
        ((unsigned short*)hbuf)[((size_t)(par ^ 1)*128 + bglob)*64 + jt] = v16;
      }

      // prefetch next step's (input-static) masks/x/D into registers;
      // loads complete while we wait at the barrier
      unsigned mreg[8], xreg[2];
      int dreg = 0;
      #pragma unroll
      for (int i = 0; i < 8; i++){
        int q = tid + i*NTHR;
        int r = q >> 6, qq = q & 63;
        int c = (r >> 4)*1024 + j0 + (r & 15);
        mreg[i] = msrc[((size_t)(t+1)*4096 + c)*64 + qq];
      }
      #pragma unroll
      for (int i = 0; i < 2; i++){
        int q = tid + i*NTHR;
        int bb = q >> 5, w = q & 31;
        xreg[i] = xp[((size_t)(t+1)*128 + b0 + bb)*32 + w];
      }
      if (tid < 64){
        int c = (tid >> 4)*1024 + j0 + (tid & 15);
        dreg = Dt[(t+1)*4096 + c];
      }

      gbar_bg(ws, bg, rep, (unsigned)(t + 1));

      // commit prefetched regs -> LDS, stage fresh h bits
      #pragma unroll
      for (int i = 0; i < 8; i++){
        int q = tid + i*NTHR;
        int r = q >> 6, qq = q & 63;
        mlds[r*66 + qq] = mreg[i];
      }
      #pragma unroll
      for (int i = 0; i < 2; i++){
        int q = tid + i*NTHR;
        int bb = q >> 5, w = q & 31;
        sm.l.xb[bb*33 + w] = xreg[i];
        sm.l.hb[bb*33 + w] = hbuf[(size_t)(par ^ 1)*4096 + (size_t)(b0 + bb)*32 + w];
      }
      if (tid < 64) sm.l.dl[tid] = dreg;
      __syncthreads();
    }
  }
}

extern "C" void kernel_launch(void* const* d_in, const int* in_sizes, int n_in,
                              void* d_out, int out_size, void* d_ws, size_t ws_size,
                              hipStream_t stream)
{
  (void)in_sizes; (void)n_in; (void)out_size; (void)ws_size;
  const float* x   = (const float*)d_in[0];
  const float* hx0 = (const float*)d_in[1];
  const float* wih = (const float*)d_in[2];
  const float* bih = (const float*)d_in[3];
  const float* whh = (const float*)d_in[4];
  const float* bhh = (const float*)d_in[5];
  float* out = (float*)d_out;
  unsigned char* ws = (unsigned char*)d_ws;

  // reset barrier counters/flags every call (graph-replay safe)
  hipMemsetAsync(d_ws, 0, 8192, stream);

  void* args[] = { (void*)&x, (void*)&hx0, (void*)&wih, (void*)&bih,
                   (void*)&whh, (void*)&bhh, (void*)&out, (void*)&ws };
  hipLaunchCooperativeKernel(reinterpret_cast<void*>(fsu_kernel),
                             dim3(NBLK), dim3(NTHR), args, 0, stream);
}

// Round 4
// 520.835 us; speedup vs baseline: 6.4348x; 5.3636x over previous
//
#include <hip/hip_runtime.h>

// FSU-MGU cell: exact integer reimplementation.
// Gate(b,c,t) = popc(bits_b & pos_{t,c}) - popc(bits_b & neg_{t,c}) + D_{t,c}
// pos: src>max(rp,ri), neg: src<=min(rp,ri), D = 1024 - #(src>ri) + (src_bias>rp).
// Main loop is fence-free: cross-block h traffic uses RETURNING agent-scope
// atomics (result consumed -> proven executed at LLC before the epoch publish)
// and explicit sc0+sc1 bypass loads (read straight from LLC). Full fences only
// in the 2 setup barriers.

#define NBLK 256
#define NTHR 512

// workspace layout (bytes); [0,8192) zeroed by hipMemsetAsync each call
#define WS_BAR_SUB   0u        // 8 counter lines, stride 128 (setup barrier)
#define WS_BAR_MST   1024u     // master counter (setup barrier)
#define WS_BAR_FLG   2048u     // 8 flag lines (setup barrier)
#define WS_HDONE  4096u        // 4 bg x 64 jt epoch slots (u32) = 1024 B
#define WS_RNGW   8192u
#define WS_RNGWI  9216u
#define WS_RNGM   10240u
#define WS_SRCB   12288u       // 4096 u16
#define WS_SRCW   20480u       // 4096*1024 u16 = 8,388,608
#define WS_XP     8409088u     // 64*128*32 u32 = 1,048,576
#define WS_HW     9457664u     // 2 par * 4 bg * 64 jt * 16 u32 = 32,768
#define WS_DT     9490432u     // 64*4096 i32 = 1,048,576
#define WS_MASKS  10539008u    // 64*4096*64 u32 = 67,108,864  (end 77,647,872)

struct SRng {
  unsigned mt[3][624];
  unsigned yb[3][624];
  unsigned draws[3][1248];
  int perm[3][256];
};
struct SC {
  unsigned short rows[16][1028];
  int rngw[64];
  int rngwi[64];
};
struct SL {
  unsigned long long mask2[64*34]; // row stride 34 u64 (16B-aligned rows)
  unsigned xb[32*34];
  unsigned hb[32*34];
  unsigned hraw[64*17];            // [jt][rp] padded
  int dl[64];
  int rngm[16];
};
union SU { SRng r; SC c; SL l; };

__device__ __forceinline__ unsigned mt_temper(unsigned y){
  y ^= y >> 11;
  y ^= (y << 7)  & 0x9d2c5680u;
  y ^= (y << 15) & 0xefc60000u;
  y ^= y >> 18;
  return y;
}

__device__ void mt_regen_serial(unsigned* mt){
  for (int i = 0; i < 624; i++){
    unsigned y = (mt[i] & 0x80000000u) | (mt[(i+1)%624] & 0x7fffffffu);
    mt[i] = mt[(i+397)%624] ^ (y >> 1) ^ ((y & 1u) ? 0x9908b0dfu : 0u);
  }
}

// LLC-direct 8-byte load: bypass L1 (sc0) and L2 (sc1), wait completion.
__device__ __forceinline__ unsigned long long llc_load64(const unsigned* p){
  unsigned long long v;
  asm volatile("global_load_dwordx2 %0, %1, off sc0 sc1\n\t"
               "s_waitcnt vmcnt(0)"
               : "=&v"(v) : "v"(p) : "memory");
  return v;
}

// numpy legacy RandomState: init_genrand seeding + Fisher-Yates with masked rejection.
__device__ void rng_gen(SU* sm, int* rngw, int* rngwi, int* rngm){
  const int tid = threadIdx.x;
  const int wv = tid >> 6, lane = tid & 63;
  const bool act = (wv < 3);
  if (act && lane == 0){
    unsigned* mt = sm->r.mt[wv];
    mt[0] = (unsigned)wv;  // seeds 0,1,2
    for (int i = 1; i < 624; i++)
      mt[i] = 1812433253u * (mt[i-1] ^ (mt[i-1] >> 30)) + (unsigned)i;
  }
  __syncthreads();
  for (int r = 0; r < 2; r++){
    if (act){
      unsigned* mt = sm->r.mt[wv]; unsigned* yb = sm->r.yb[wv];
      for (int i = lane; i < 623; i += 64)
        yb[i] = (mt[i] & 0x80000000u) | (mt[i+1] & 0x7fffffffu);
    }
    __syncthreads();
    if (act){
      unsigned* mt = sm->r.mt[wv]; unsigned* yb = sm->r.yb[wv];
      for (int i = lane; i < 227; i += 64){
        unsigned y = yb[i];
        mt[i] = mt[i+397] ^ (y >> 1) ^ ((y & 1u) ? 0x9908b0dfu : 0u);
      }
    }
    __syncthreads();
    if (act){
      unsigned* mt = sm->r.mt[wv]; unsigned* yb = sm->r.yb[wv];
      for (int i = 227 + lane; i < 454; i += 64){
        unsigned y = yb[i];
        mt[i] = mt[i-227] ^ (y >> 1) ^ ((y & 1u) ? 0x9908b0dfu : 0u);
      }
    }
    __syncthreads();
    if (act){
      unsigned* mt = sm->r.mt[wv]; unsigned* yb = sm->r.yb[wv];
      for (int i = 454 + lane; i < 624; i += 64){
        unsigned y = (i < 623) ? yb[i]
                   : ((mt[623] & 0x80000000u) | (mt[0] & 0x7fffffffu));
        mt[i] = mt[i-227] ^ (y >> 1) ^ ((y & 1u) ? 0x9908b0dfu : 0u);
      }
    }
    __syncthreads();
    if (act){
      unsigned* mt = sm->r.mt[wv];
      for (int i = lane; i < 624; i += 64)
        sm->r.draws[wv][r*624 + i] = mt_temper(mt[i]);
    }
    __syncthreads();
  }
  if (act && lane == 0){
    const int n = (wv == 2) ? 16 : 256;
    int* perm = sm->r.perm[wv];
    for (int i = 0; i < n; i++) perm[i] = i;
    int dp = 0, spos = 624;
    unsigned* mt = sm->r.mt[wv];
    for (int i = n - 1; i > 0; i--){
      unsigned mask = (unsigned)i;
      mask |= mask >> 1; mask |= mask >> 2; mask |= mask >> 4;
      mask |= mask >> 8; mask |= mask >> 16;
      unsigned v;
      do {
        unsigned d;
        if (dp < 1248) d = sm->r.draws[wv][dp++];
        else {
          if (spos >= 624){ mt_regen_serial(mt); spos = 0; }
          d = mt_temper(mt[spos++]);
        }
        v = d & mask;
      } while (v > (unsigned)i);
      int tmp = perm[i]; perm[i] = perm[v]; perm[v] = tmp;
    }
    int* dst = (wv == 0) ? rngw : (wv == 1) ? rngwi : rngm;
    for (int i = 0; i < n; i++) dst[i] = perm[i];
  }
}

// full-grid barrier WITH fences — setup phases only (publishes normal stores)
__device__ __forceinline__ void gbar_full(unsigned char* ws, unsigned ep){
  __syncthreads();
  if (threadIdx.x == 0){
    __threadfence();
    unsigned* sub = (unsigned*)(ws + WS_BAR_SUB + (blockIdx.x & 7)*128);
    unsigned old = atomicAdd(sub, 1u);
    if (old == ep*32u - 1u){
      unsigned* mst = (unsigned*)(ws + WS_BAR_MST);
      unsigned mo = atomicAdd(mst, 1u);
      if (mo == ep*8u - 1u){
        for (int i = 0; i < 8; i++)
          __hip_atomic_store((unsigned*)(ws + WS_BAR_FLG + i*128), ep,
                             __ATOMIC_RELAXED, __HIP_MEMORY_SCOPE_AGENT);
      }
    }
    const unsigned* fl = (const unsigned*)(ws + WS_BAR_FLG + (blockIdx.x & 7)*128);
    while (__hip_atomic_load(fl, __ATOMIC_RELAXED, __HIP_MEMORY_SCOPE_AGENT) < ep)
      __builtin_amdgcn_s_sleep(8);
  }
  __syncthreads();
  __threadfence();
}

__device__ __forceinline__ int clampi(int v){
  v = v < -512 ? -512 : v;
  v = v >  512 ?  512 : v;
  return v;
}

__global__ void __launch_bounds__(NTHR)
fsu_kernel(const float* __restrict__ x, const float* __restrict__ hx0,
           const float* __restrict__ wih, const float* __restrict__ bih,
           const float* __restrict__ whh, const float* __restrict__ bhh,
           float* __restrict__ out, unsigned char* __restrict__ ws)
{
  __shared__ SU sm;
  const int tid = threadIdx.x;
  const int bid = blockIdx.x;

  int* rngw  = (int*)(ws + WS_RNGW);
  int* rngwi = (int*)(ws + WS_RNGWI);
  int* rngm  = (int*)(ws + WS_RNGM);
  unsigned short* srcb = (unsigned short*)(ws + WS_SRCB);
  unsigned short* srcw = (unsigned short*)(ws + WS_SRCW);
  unsigned* xp   = (unsigned*)(ws + WS_XP);
  unsigned* hw   = (unsigned*)(ws + WS_HW);
  unsigned* hdone = (unsigned*)(ws + WS_HDONE);
  int* Dt = (int*)(ws + WS_DT);
  unsigned long long* masks = (unsigned long long*)(ws + WS_MASKS);

  // ---------- phase 0: RNG tables (block 0) || bit-pack + src build (others)
  if (bid == 0){
    rng_gen(&sm, rngw, rngwi, rngm);
  } else {
    const int gtid = (bid - 1)*NTHR + tid;
    const int lane = tid & 63;
    const int gw = gtid >> 6;
    const int nw = (NBLK-1)*(NTHR/64);
    const int nthr = (NBLK-1)*NTHR;
    for (int ch = gw; ch < 131072; ch += nw){            // x bits
      float v = x[(size_t)ch*64 + lane];
      unsigned long long bal = __ballot(v != 0.0f);
      if ((lane & 31) == 0) xp[ch*2 + (lane >> 5)] = (unsigned)(bal >> lane);
    }
    for (int idx = gtid; idx < 4096; idx += nthr){       // initial h (par 0), packed
      int bg2 = idx >> 10, jt2 = (idx >> 4) & 63, rp2 = idx & 15;
      int r0 = bg2*32 + 2*rp2;
      unsigned v = 0;
      for (int j = 0; j < 16; j++){
        v |= (hx0[(size_t)r0*1024 + jt2*16 + j] != 0.0f) ? (1u<<j) : 0u;
        v |= (hx0[(size_t)(r0+1)*1024 + jt2*16 + j] != 0.0f) ? (1u<<(16+j)) : 0u;
      }
      hw[idx] = v;   // normal store; flushed to LLC by gbar_full's release fence
    }
    for (int idx = gtid; idx < 4096*1024; idx += nthr){  // src = round((clip+1)*128)
      int c = idx >> 10, k = idx & 1023;
      float wv2 = (c < 2048) ? wih[(size_t)c*1024 + k] : whh[(size_t)(c - 2048)*1024 + k];
      float cl = fminf(fmaxf(wv2, -1.0f), 1.0f);
      srcw[idx] = (unsigned short)(int)rintf((cl + 1.0f)*0.5f*256.0f);
    }
    for (int c = gtid; c < 4096; c += nthr){
      float bv = (c < 2048) ? bih[c] : bhh[c - 2048];
      float cl = fminf(fmaxf(bv, -1.0f), 1.0f);
      srcb[c] = (unsigned short)(int)rintf((cl + 1.0f)*0.5f*256.0f);
    }
  }
  gbar_full(ws, 1u);

  // ---------- phase C: pos/neg masks + D constants for all (t, col)
  {
    const int c0 = bid * 16;
    const unsigned* srcw32 = (const unsigned*)srcw;
    for (int q = tid; q < 16*512; q += NTHR){
      int r = q >> 9, w = q & 511;
      ((unsigned*)&sm.c.rows[r][0])[w] = srcw32[(size_t)(c0 + r)*512 + w];
    }
    if (tid < 64) sm.c.rngw[tid] = rngw[tid];
    if (tid >= 64 && tid < 128) sm.c.rngwi[tid - 64] = rngwi[tid - 64];
    __syncthreads();
    for (int rr = 0; rr < 2; rr++){
      int row = tid + rr*NTHR;            // 0..1023 : (t, local col)
      int t = row >> 4, lc = row & 15, col = c0 + lc;
      int rp = sm.c.rngw[t], ri = sm.c.rngwi[t];
      int hi = rp > ri ? rp : ri;
      int lo1 = (rp < ri ? rp : ri) + 1;
      bool rihi = (ri >= rp);
      const unsigned* srow = (const unsigned*)&sm.c.rows[lc][0];
      unsigned long long* gdst = masks + ((size_t)t*4096 + col)*32;
      int cnti = 0;
      for (int w = 0; w < 32; w++){
        unsigned pos = 0, neg = 0;
        #pragma unroll
        for (int i2 = 15; i2 >= 0; i2--){
          unsigned v2 = srow[w*16 + i2];
          int vH = (int)(v2 >> 16);
          int vL = (int)(v2 & 0xFFFFu);
          pos = (pos << 1) | ((unsigned)(hi - vH) >> 31);   // v > hi
          neg = (neg << 1) | ((unsigned)(vH - lo1) >> 31);  // v <= lo
          pos = (pos << 1) | ((unsigned)(hi - vL) >> 31);
          neg = (neg << 1) | ((unsigned)(vL - lo1) >> 31);
        }
        gdst[w] = (unsigned long long)pos | ((unsigned long long)neg << 32);
        cnti += rihi ? __popc(pos) : (32 - __popc(neg));    // count(src > ri)
      }
      Dt[t*4096 + col] = 1024 - cnti + (((int)srcb[col] > rp) ? 1 : 0);
    }
  }
  gbar_full(ws, 2u);

  // ---------- main recurrence
  // jt = bid & 63 so the 4 bg-siblings of a jt land on the same XCD (bid%8 law)
  const int jt = bid & 63, bg = bid >> 6;
  const int j0 = jt * 16, b0 = bg * 32;
  const int b_l = tid >> 4, j_l = tid & 15;
  const int bglob = b0 + b_l;

  int hcur = (hx0[(size_t)bglob*1024 + j0 + j_l] != 0.0f) ? 1 : 0;
  int A1=0,A2=0,A3=0,A4=0,A5=0,A6=0;          // 2x-scaled accumulators
  unsigned sr1=10u, sr2=10u, sr3=10u;          // shift regs, init [0,1,0,1]
  int i1p=0,i1i=0,i2p=0,i2i=0,i3p=0,i3i=0;

  if (tid < 16) sm.l.rngm[tid] = rngm[tid];

  const unsigned* msrc = (const unsigned*)masks;
  unsigned* mlds = (unsigned*)sm.l.mask2;

  // prime stage for t=0
  {
    #pragma unroll
    for (int i = 0; i < 8; i++){
      int q = tid + i*NTHR;
      int r = q >> 6, qq = q & 63;
      int c = (r >> 4)*1024 + j0 + (r & 15);
      mlds[r*68 + qq] = msrc[((size_t)0*4096 + c)*64 + qq];
    }
    #pragma unroll
    for (int i = 0; i < 2; i++){
      int q = tid + i*NTHR;
      int bb = q >> 5, w = q & 31;
      sm.l.xb[bb*34 + w] = xp[((size_t)0*128 + b0 + bb)*32 + w];
    }
    {
      unsigned long long hv = llc_load64(&hw[bg*1024 + 2*tid]);
      int q0 = 2*tid, q1 = 2*tid + 1;
      sm.l.hraw[(q0 >> 4)*17 + (q0 & 15)] = (unsigned)hv;
      sm.l.hraw[(q1 >> 4)*17 + (q1 & 15)] = (unsigned)(hv >> 32);
    }
    if (tid < 64){
      int c = (tid >> 4)*1024 + j0 + (tid & 15);
      sm.l.dl[tid] = Dt[0*4096 + c];
    }
    __syncthreads();
    #pragma unroll
    for (int i = 0; i < 2; i++){
      int idx = tid + i*NTHR;
      int bb = idx >> 5, w = idx & 31;
      int rp = bb >> 1, sh = (bb & 1) << 4;
      unsigned lo = (sm.l.hraw[(2*w)*17 + rp] >> sh) & 0xFFFFu;
      unsigned hi = (sm.l.hraw[(2*w + 1)*17 + rp] >> sh) & 0xFFFFu;
      sm.l.hb[bb*34 + w] = lo | (hi << 16);
    }
    __syncthreads();
  }

  for (int t = 0; t < 64; t++){
    const int par = t & 1;

    int p0=0,n0=0,p1=0,n1=0,p2=0,n2=0,p3=0,n3=0;
    const ulonglong2* m0p = (const ulonglong2*)&sm.l.mask2[(0*16 + j_l)*34];
    const ulonglong2* m1p = (const ulonglong2*)&sm.l.mask2[(1*16 + j_l)*34];
    const ulonglong2* m2p = (const ulonglong2*)&sm.l.mask2[(2*16 + j_l)*34];
    const ulonglong2* m3p = (const ulonglong2*)&sm.l.mask2[(3*16 + j_l)*34];
    const uint2* xrow = (const uint2*)&sm.l.xb[b_l*34];
    const uint2* hrow = (const uint2*)&sm.l.hb[b_l*34];
    #pragma unroll
    for (int w2 = 0; w2 < 16; w2++){
      uint2 xv = xrow[w2], hv = hrow[w2];
      ulonglong2 a = m0p[w2];
      p0 += __popc(xv.x & (unsigned)a.x) + __popc(xv.y & (unsigned)a.y);
      n0 += __popc(xv.x & (unsigned)(a.x >> 32)) + __popc(xv.y & (unsigned)(a.y >> 32));
      ulonglong2 b = m1p[w2];
      p1 += __popc(xv.x & (unsigned)b.x) + __popc(xv.y & (unsigned)b.y);
      n1 += __popc(xv.x & (unsigned)(b.x >> 32)) + __popc(xv.y & (unsigned)(b.y >> 32));
      ulonglong2 c2 = m2p[w2];
      p2 += __popc(hv.x & (unsigned)c2.x) + __popc(hv.y & (unsigned)c2.y);
      n2 += __popc(hv.x & (unsigned)(c2.x >> 32)) + __popc(hv.y & (unsigned)(c2.y >> 32));
      ulonglong2 d = m3p[w2];
      p3 += __popc(hv.x & (unsigned)d.x) + __popc(hv.y & (unsigned)d.y);
      n3 += __popc(hv.x & (unsigned)(d.x >> 32)) + __popc(hv.y & (unsigned)(d.y >> 32));
    }
    const int g_if = sm.l.dl[0*16 + j_l] + p0 - n0;
    const int g_in = sm.l.dl[1*16 + j_l] + p1 - n1;
    const int g_hf = sm.l.dl[2*16 + j_l] + p2 - n2;
    const int g_hn = sm.l.dl[3*16 + j_l] + p3 - n3;

    // ---- FSU elementwise chain (exact, 2x-scaled ints)
    int s1 = g_if + g_hf;
    A1 = clampi(A1 + 2*s1 - 2049);                 // off_fg = 1024.5
    int fg_in = (A1 >= 2); A1 -= fg_in << 1;
    A2 = clampi(A2 + ((fg_in + 1) << 1));          // off 0, scale 2
    int fg = (A2 >= 4); A2 -= fg << 2;
    A3 = clampi(A3 + (g_hn << 1) - 1024);          // off 512
    int hnb = (A3 >= 2); A3 -= hnb << 1;

    sr1 = ((sr1 >> 1) | ((unsigned)hnb << 3)) & 0xFu;
    int ng_prod;
    {
      int cv = __popc(sr1) << 2;
      int bp = cv > sm.l.rngm[i1p & 15];
      int bi = cv > sm.l.rngm[i1i & 15];
      ng_prod = fg ? bp : (1 - bi);
      i1p += fg; i1i += 1 - fg;
    }
    A4 = clampi(A4 + (g_in << 1) - 1024);          // off 512
    int inb = (A4 >= 2); A4 -= inb << 1;
    A5 = clampi(A5 + ((inb + ng_prod) << 1) - 1);  // off 0.5
    int ng = (A5 >= 2); A5 -= ng << 1;

    sr2 = ((sr2 >> 1) | ((unsigned)ng << 3)) & 0xFu;
    int fgi;
    {
      int cv = __popc(sr2) << 2;
      int bp = cv > sm.l.rngm[i2p & 15];
      int bi = cv > sm.l.rngm[i2i & 15];
      fgi = (1 - fg) ? bp : (1 - bi);              // in0 = 1-fg
      i2p += 1 - fg; i2i += fg;
    }
    sr3 = ((sr3 >> 1) | ((unsigned)hcur << 3)) & 0xFu;
    int fgp;
    {
      int cv = __popc(sr3) << 2;
      int bp = cv > sm.l.rngm[i3p & 15];
      int bi = cv > sm.l.rngm[i3i & 15];
      fgp = fg ? bp : (1 - bi);                    // in0 = fg
      i3p += fg; i3i += 1 - fg;
    }
    A6 = clampi(A6 + ((ng + fgi + fgp) << 1) - 2); // off 1.0
    int hy = (A6 >= 2); A6 -= hy << 1;

    out[(size_t)t*131072 + (size_t)bglob*1024 + j0 + j_l] = (float)hy;
    hcur = hy;

    if (t < 63){
      // publish h bits for step t+1: RETURNING exchange, result consumed ->
      // wave provably waits until the swap has EXECUTED at the LLC.
      unsigned long long bal = __ballot(hy);
      if ((tid & 31) == 0){
        unsigned v = (unsigned)(bal >> (tid & 32));
        unsigned old = atomicExch(
            &hw[((par ^ 1)*4 + bg)*1024 + jt*16 + (tid >> 5)], v);
        asm volatile("" :: "v"(old));
      }
      __syncthreads();   // S1: all waves' swaps confirmed-at-LLC before this
      if (tid == 0){
        unsigned old2 = atomicExch(&hdone[bg*64 + jt], (unsigned)(t + 1));
        asm volatile("" :: "v"(old2));
      }

      // prefetch next step's (immutable) masks/x/D into regs; complete during poll
      unsigned mreg[8], xreg[2];
      int dreg = 0;
      #pragma unroll
      for (int i = 0; i < 8; i++){
        int q = tid + i*NTHR;
        int r = q >> 6, qq = q & 63;
        int c = (r >> 4)*1024 + j0 + (r & 15);
        mreg[i] = msrc[((size_t)(t+1)*4096 + c)*64 + qq];
      }
      #pragma unroll
      for (int i = 0; i < 2; i++){
        int q = tid + i*NTHR;
        int bb = q >> 5, w = q & 31;
        xreg[i] = xp[((size_t)(t+1)*128 + b0 + bb)*32 + w];
      }
      if (tid < 64){
        int c = (tid >> 4)*1024 + j0 + (tid & 15);
        dreg = Dt[(t+1)*4096 + c];
      }

      // distributed barrier: wave 0 polls all 64 sibling epoch slots
      if (tid < 64){
        const unsigned ep = (unsigned)(t + 1);
        unsigned* slot = hdone + bg*64 + tid;
        while (true){
          unsigned v = __hip_atomic_load(slot, __ATOMIC_RELAXED,
                                         __HIP_MEMORY_SCOPE_AGENT);
          if (__all((int)(v >= ep))) break;
          __builtin_amdgcn_s_sleep(1);
        }
      }
      __syncthreads();   // S2

      // pull fresh h chunks (LLC-direct sc0+sc1 loads) + commit prefetched regs
      {
        unsigned long long hv =
            llc_load64(&hw[((par ^ 1)*4 + bg)*1024 + 2*tid]);
        int q0 = 2*tid, q1 = 2*tid + 1;
        sm.l.hraw[(q0 >> 4)*17 + (q0 & 15)] = (unsigned)hv;
        sm.l.hraw[(q1 >> 4)*17 + (q1 & 15)] = (unsigned)(hv >> 32);
      }
      #pragma unroll
      for (int i = 0; i < 8; i++){
        int q = tid + i*NTHR;
        int r = q >> 6, qq = q & 63;
        mlds[r*68 + qq] = mreg[i];
      }
      #pragma unroll
      for (int i = 0; i < 2; i++){
        int q = tid + i*NTHR;
        int bb = q >> 5, w = q & 31;
        sm.l.xb[bb*34 + w] = xreg[i];
      }
      if (tid < 64) sm.l.dl[tid] = dreg;
      __syncthreads();   // S3: hraw + LDS commits visible

      #pragma unroll
      for (int i = 0; i < 2; i++){
        int idx = tid + i*NTHR;
        int bb = idx >> 5, w = idx & 31;
        int rp = bb >> 1, sh = (bb & 1) << 4;
        unsigned lo = (sm.l.hraw[(2*w)*17 + rp] >> sh) & 0xFFFFu;
        unsigned hi = (sm.l.hraw[(2*w + 1)*17 + rp] >> sh) & 0xFFFFu;
        sm.l.hb[bb*34 + w] = lo | (hi << 16);
      }
      __syncthreads();   // S4: hb ready
    }
  }
}

extern "C" void kernel_launch(void* const* d_in, const int* in_sizes, int n_in,
                              void* d_out, int out_size, void* d_ws, size_t ws_size,
                              hipStream_t stream)
{
  (void)in_sizes; (void)n_in; (void)out_size; (void)ws_size;
  const float* x   = (const float*)d_in[0];
  const float* hx0 = (const float*)d_in[1];
  const float* wih = (const float*)d_in[2];
  const float* bih = (const float*)d_in[3];
  const float* whh = (const float*)d_in[4];
  const float* bhh = (const float*)d_in[5];
  float* out = (float*)d_out;
  unsigned char* ws = (unsigned char*)d_ws;

  // reset barrier counters + epoch slots every call (graph-replay safe)
  hipMemsetAsync(d_ws, 0, 8192, stream);

  void* args[] = { (void*)&x, (void*)&hx0, (void*)&wih, (void*)&bih,
                   (void*)&whh, (void*)&bhh, (void*)&out, (void*)&ws };
  hipLaunchCooperativeKernel(reinterpret_cast<void*>(fsu_kernel),
                             dim3(NBLK), dim3(NTHR), args, 0, stream);
}

// Round 5
// 517.783 us; speedup vs baseline: 6.4727x; 1.0059x over previous
//
#include <hip/hip_runtime.h>

// FSU-MGU cell: exact integer reimplementation.
// Gate(b,c,t) = popc(bits_b & pos_{t,c}) - popc(bits_b & neg_{t,c}) + D_{t,c}
// pos: src>max(rp,ri), neg: src<=min(rp,ri), D = 1024 - #(src>ri) + (src_bias>rp).
// Main loop is fence-free. Cross-block h traffic: each 32-bit h chunk is
// published as ONE u64 agent-scope atomic store {tag=t+1 | data} -- tag and
// data in the same atomic word, so no publish/flag ordering is needed at all.
// Readers poll a representative slot per publisher (wave 0), then pull-verify
// every slot by its own embedded tag. Parity double-buffer + causality make
// slot reuse safe. Full fences only in the 2 setup barriers.

#define NBLK 256
#define NTHR 512

// workspace layout (bytes); [0,4096) and hw region zeroed each call
#define WS_BAR_SUB   0u        // 8 counter lines, stride 128 (setup barrier)
#define WS_BAR_MST   1024u     // master counter (setup barrier)
#define WS_BAR_FLG   2048u     // 8 flag lines (setup barrier)
#define WS_RNGW   8192u
#define WS_RNGWI  9216u
#define WS_RNGM   10240u
#define WS_SRCB   12288u       // 4096 u16
#define WS_SRCW   20480u       // 4096*1024 u16 = 8,388,608 (end 8,409,088)
#define WS_XP     8409088u     // 64*128*32 u32 = 1,048,576 (end 9,457,664)
#define WS_HW     9457664u     // 2 par * 4 bg * 64 jt * 16 u64 slots = 65,536
#define WS_DT     9523200u     // 64*4096 i32 = 1,048,576 (end 10,571,776)
#define WS_MASKS  10571776u    // 64*4096*64 u32 = 67,108,864 (end 77,680,640)

struct SRng {
  unsigned mt[3][624];
  unsigned yb[3][624];
  unsigned draws[3][1248];
  int perm[3][256];
};
struct SC {
  unsigned short rows[16][1028];
  int rngw[64];
  int rngwi[64];
};
struct SL {
  unsigned long long mask2[64*34]; // row stride 34 u64 (16B-aligned rows)
  unsigned xb[32*34];
  unsigned hb[32*34];
  unsigned hraw[64*17];            // [jt][bpair] padded
  int dl[64];
  int rngm[16];
};
union SU { SRng r; SC c; SL l; };

__device__ __forceinline__ unsigned mt_temper(unsigned y){
  y ^= y >> 11;
  y ^= (y << 7)  & 0x9d2c5680u;
  y ^= (y << 15) & 0xefc60000u;
  y ^= y >> 18;
  return y;
}

__device__ void mt_regen_serial(unsigned* mt){
  for (int i = 0; i < 624; i++){
    unsigned y = (mt[i] & 0x80000000u) | (mt[(i+1)%624] & 0x7fffffffu);
    mt[i] = mt[(i+397)%624] ^ (y >> 1) ^ ((y & 1u) ? 0x9908b0dfu : 0u);
  }
}

// numpy legacy RandomState: init_genrand seeding + Fisher-Yates with masked rejection.
__device__ void rng_gen(SU* sm, int* rngw, int* rngwi, int* rngm){
  const int tid = threadIdx.x;
  const int wv = tid >> 6, lane = tid & 63;
  const bool act = (wv < 3);
  if (act && lane == 0){
    unsigned* mt = sm->r.mt[wv];
    mt[0] = (unsigned)wv;  // seeds 0,1,2
    for (int i = 1; i < 624; i++)
      mt[i] = 1812433253u * (mt[i-1] ^ (mt[i-1] >> 30)) + (unsigned)i;
  }
  __syncthreads();
  for (int r = 0; r < 2; r++){
    if (act){
      unsigned* mt = sm->r.mt[wv]; unsigned* yb = sm->r.yb[wv];
      for (int i = lane; i < 623; i += 64)
        yb[i] = (mt[i] & 0x80000000u) | (mt[i+1] & 0x7fffffffu);
    }
    __syncthreads();
    if (act){
      unsigned* mt = sm->r.mt[wv]; unsigned* yb = sm->r.yb[wv];
      for (int i = lane; i < 227; i += 64){
        unsigned y = yb[i];
        mt[i] = mt[i+397] ^ (y >> 1) ^ ((y & 1u) ? 0x9908b0dfu : 0u);
      }
    }
    __syncthreads();
    if (act){
      unsigned* mt = sm->r.mt[wv]; unsigned* yb = sm->r.yb[wv];
      for (int i = 227 + lane; i < 454; i += 64){
        unsigned y = yb[i];
        mt[i] = mt[i-227] ^ (y >> 1) ^ ((y & 1u) ? 0x9908b0dfu : 0u);
      }
    }
    __syncthreads();
    if (act){
      unsigned* mt = sm->r.mt[wv]; unsigned* yb = sm->r.yb[wv];
      for (int i = 454 + lane; i < 624; i += 64){
        unsigned y = (i < 623) ? yb[i]
                   : ((mt[623] & 0x80000000u) | (mt[0] & 0x7fffffffu));
        mt[i] = mt[i-227] ^ (y >> 1) ^ ((y & 1u) ? 0x9908b0dfu : 0u);
      }
    }
    __syncthreads();
    if (act){
      unsigned* mt = sm->r.mt[wv];
      for (int i = lane; i < 624; i += 64)
        sm->r.draws[wv][r*624 + i] = mt_temper(mt[i]);
    }
    __syncthreads();
  }
  if (act && lane == 0){
    const int n = (wv == 2) ? 16 : 256;
    int* perm = sm->r.perm[wv];
    for (int i = 0; i < n; i++) perm[i] = i;
    int dp = 0, spos = 624;
    unsigned* mt = sm->r.mt[wv];
    for (int i = n - 1; i > 0; i--){
      unsigned mask = (unsigned)i;
      mask |= mask >> 1; mask |= mask >> 2; mask |= mask >> 4;
      mask |= mask >> 8; mask |= mask >> 16;
      unsigned v;
      do {
        unsigned d;
        if (dp < 1248) d = sm->r.draws[wv][dp++];
        else {
          if (spos >= 624){ mt_regen_serial(mt); spos = 0; }
          d = mt_temper(mt[spos++]);
        }
        v = d & mask;
      } while (v > (unsigned)i);
      int tmp = perm[i]; perm[i] = perm[v]; perm[v] = tmp;
    }
    int* dst = (wv == 0) ? rngw : (wv == 1) ? rngwi : rngm;
    for (int i = 0; i < n; i++) dst[i] = perm[i];
  }
}

// full-grid barrier WITH fences — setup phases only (publishes normal stores)
__device__ __forceinline__ void gbar_full(unsigned char* ws, unsigned ep){
  __syncthreads();
  if (threadIdx.x == 0){
    __threadfence();
    unsigned* sub = (unsigned*)(ws + WS_BAR_SUB + (blockIdx.x & 7)*128);
    unsigned old = atomicAdd(sub, 1u);
    if (old == ep*32u - 1u){
      unsigned* mst = (unsigned*)(ws + WS_BAR_MST);
      unsigned mo = atomicAdd(mst, 1u);
      if (mo == ep*8u - 1u){
        for (int i = 0; i < 8; i++)
          __hip_atomic_store((unsigned*)(ws + WS_BAR_FLG + i*128), ep,
                             __ATOMIC_RELAXED, __HIP_MEMORY_SCOPE_AGENT);
      }
    }
    const unsigned* fl = (const unsigned*)(ws + WS_BAR_FLG + (blockIdx.x & 7)*128);
    while (__hip_atomic_load(fl, __ATOMIC_RELAXED, __HIP_MEMORY_SCOPE_AGENT) < ep)
      __builtin_amdgcn_s_sleep(8);
  }
  __syncthreads();
  __threadfence();
}

__device__ __forceinline__ int clampi(int v){
  v = v < -512 ? -512 : v;
  v = v >  512 ?  512 : v;
  return v;
}

__global__ void __launch_bounds__(NTHR)
fsu_kernel(const float* __restrict__ x, const float* __restrict__ hx0,
           const float* __restrict__ wih, const float* __restrict__ bih,
           const float* __restrict__ whh, const float* __restrict__ bhh,
           float* __restrict__ out, unsigned char* __restrict__ ws)
{
  __shared__ SU sm;
  const int tid = threadIdx.x;
  const int bid = blockIdx.x;

  int* rngw  = (int*)(ws + WS_RNGW);
  int* rngwi = (int*)(ws + WS_RNGWI);
  int* rngm  = (int*)(ws + WS_RNGM);
  unsigned short* srcb = (unsigned short*)(ws + WS_SRCB);
  unsigned short* srcw = (unsigned short*)(ws + WS_SRCW);
  unsigned* xp   = (unsigned*)(ws + WS_XP);
  unsigned long long* hw = (unsigned long long*)(ws + WS_HW);
  int* Dt = (int*)(ws + WS_DT);
  unsigned long long* masks = (unsigned long long*)(ws + WS_MASKS);

  // ---------- phase 0: RNG tables (block 0) || bit-pack + src build (others)
  if (bid == 0){
    rng_gen(&sm, rngw, rngwi, rngm);
  } else {
    const int gtid = (bid - 1)*NTHR + tid;
    const int lane = tid & 63;
    const int gw = gtid >> 6;
    const int nw = (NBLK-1)*(NTHR/64);
    const int nthr = (NBLK-1)*NTHR;
    for (int ch = gw; ch < 131072; ch += nw){            // x bits
      float v = x[(size_t)ch*64 + lane];
      unsigned long long bal = __ballot(v != 0.0f);
      if ((lane & 31) == 0) xp[ch*2 + (lane >> 5)] = (unsigned)(bal >> lane);
    }
    for (int idx = gtid; idx < 4096; idx += nthr){       // initial h slots (par 0, tag 0)
      int bg2 = idx >> 10, jt2 = (idx >> 4) & 63, rp2 = idx & 15;
      int r0 = bg2*32 + 2*rp2;
      unsigned v = 0;
      for (int j = 0; j < 16; j++){
        v |= (hx0[(size_t)r0*1024 + jt2*16 + j] != 0.0f) ? (1u<<j) : 0u;
        v |= (hx0[(size_t)(r0+1)*1024 + jt2*16 + j] != 0.0f) ? (1u<<(16+j)) : 0u;
      }
      hw[idx] = (unsigned long long)v;  // tag 0; flushed by gbar_full fence
    }
    for (int idx = gtid; idx < 4096*1024; idx += nthr){  // src = round((clip+1)*128)
      int c = idx >> 10, k = idx & 1023;
      float wv2 = (c < 2048) ? wih[(size_t)c*1024 + k] : whh[(size_t)(c - 2048)*1024 + k];
      float cl = fminf(fmaxf(wv2, -1.0f), 1.0f);
      srcw[idx] = (unsigned short)(int)rintf((cl + 1.0f)*0.5f*256.0f);
    }
    for (int c = gtid; c < 4096; c += nthr){
      float bv = (c < 2048) ? bih[c] : bhh[c - 2048];
      float cl = fminf(fmaxf(bv, -1.0f), 1.0f);
      srcb[c] = (unsigned short)(int)rintf((cl + 1.0f)*0.5f*256.0f);
    }
  }
  gbar_full(ws, 1u);

  // ---------- phase C: pos/neg masks + D constants for all (t, col)
  {
    const int c0 = bid * 16;
    const unsigned* srcw32 = (const unsigned*)srcw;
    for (int q = tid; q < 16*512; q += NTHR){
      int r = q >> 9, w = q & 511;
      ((unsigned*)&sm.c.rows[r][0])[w] = srcw32[(size_t)(c0 + r)*512 + w];
    }
    if (tid < 64) sm.c.rngw[tid] = rngw[tid];
    if (tid >= 64 && tid < 128) sm.c.rngwi[tid - 64] = rngwi[tid - 64];
    __syncthreads();
    for (int rr = 0; rr < 2; rr++){
      int row = tid + rr*NTHR;            // 0..1023 : (t, local col)
      int t = row >> 4, lc = row & 15, col = c0 + lc;
      int rp = sm.c.rngw[t], ri = sm.c.rngwi[t];
      int hi = rp > ri ? rp : ri;
      int lo1 = (rp < ri ? rp : ri) + 1;
      bool rihi = (ri >= rp);
      const unsigned* srow = (const unsigned*)&sm.c.rows[lc][0];
      unsigned long long* gdst = masks + ((size_t)t*4096 + col)*32;
      int cnti = 0;
      for (int w = 0; w < 32; w++){
        unsigned pos = 0, neg = 0;
        #pragma unroll
        for (int i2 = 15; i2 >= 0; i2--){
          unsigned v2 = srow[w*16 + i2];
          int vH = (int)(v2 >> 16);
          int vL = (int)(v2 & 0xFFFFu);
          pos = (pos << 1) | ((unsigned)(hi - vH) >> 31);   // v > hi
          neg = (neg << 1) | ((unsigned)(vH - lo1) >> 31);  // v <= lo
          pos = (pos << 1) | ((unsigned)(hi - vL) >> 31);
          neg = (neg << 1) | ((unsigned)(vL - lo1) >> 31);
        }
        gdst[w] = (unsigned long long)pos | ((unsigned long long)neg << 32);
        cnti += rihi ? __popc(pos) : (32 - __popc(neg));    // count(src > ri)
      }
      Dt[t*4096 + col] = 1024 - cnti + (((int)srcb[col] > rp) ? 1 : 0);
    }
  }
  gbar_full(ws, 2u);

  // ---------- main recurrence
  // jt = bid & 63: the 4 bg-siblings of a jt land on the same XCD (bid%8 law)
  const int jt = bid & 63, bg = bid >> 6;
  const int j0 = jt * 16, b0 = bg * 32;
  const int b_l = tid >> 4, j_l = tid & 15;
  const int bglob = b0 + b_l;

  int hcur = (hx0[(size_t)bglob*1024 + j0 + j_l] != 0.0f) ? 1 : 0;
  int A1=0,A2=0,A3=0,A4=0,A5=0,A6=0;          // 2x-scaled accumulators
  unsigned sr1=10u, sr2=10u, sr3=10u;          // shift regs, init [0,1,0,1]
  int i1p=0,i1i=0,i2p=0,i2i=0,i3p=0,i3i=0;

  if (tid < 16) sm.l.rngm[tid] = rngm[tid];

  const unsigned* msrc = (const unsigned*)masks;
  unsigned* mlds = (unsigned*)sm.l.mask2;

  // prime stage for t=0 (parity-0 slots, coherent after setup fence)
  {
    #pragma unroll
    for (int i = 0; i < 8; i++){
      int q = tid + i*NTHR;
      int r = q >> 6, qq = q & 63;
      int c = (r >> 4)*1024 + j0 + (r & 15);
      mlds[r*68 + qq] = msrc[((size_t)0*4096 + c)*64 + qq];
    }
    #pragma unroll
    for (int i = 0; i < 2; i++){
      int q = tid + i*NTHR;
      int bb = q >> 5, w = q & 31;
      sm.l.xb[bb*34 + w] = xp[((size_t)0*128 + b0 + bb)*32 + w];
    }
    #pragma unroll
    for (int i = 0; i < 2; i++){
      int q = tid + i*NTHR;         // q = jt*16 + bpair
      unsigned long long v = __hip_atomic_load(&hw[(size_t)bg*1024 + q],
                                               __ATOMIC_RELAXED,
                                               __HIP_MEMORY_SCOPE_AGENT);
      sm.l.hraw[(q >> 4)*17 + (q & 15)] = (unsigned)v;
    }
    if (tid < 64){
      int c = (tid >> 4)*1024 + j0 + (tid & 15);
      sm.l.dl[tid] = Dt[0*4096 + c];
    }
    __syncthreads();
    #pragma unroll
    for (int i = 0; i < 2; i++){
      int idx = tid + i*NTHR;
      int bb = idx >> 5, w = idx & 31;
      int rp = bb >> 1, sh = (bb & 1) << 4;
      unsigned lo = (sm.l.hraw[(2*w)*17 + rp] >> sh) & 0xFFFFu;
      unsigned hi = (sm.l.hraw[(2*w + 1)*17 + rp] >> sh) & 0xFFFFu;
      sm.l.hb[bb*34 + w] = lo | (hi << 16);
    }
    __syncthreads();
  }

  for (int t = 0; t < 64; t++){
    const int par = t & 1;

    int p0=0,n0=0,p1=0,n1=0,p2=0,n2=0,p3=0,n3=0;
    const ulonglong2* m0p = (const ulonglong2*)&sm.l.mask2[(0*16 + j_l)*34];
    const ulonglong2* m1p = (const ulonglong2*)&sm.l.mask2[(1*16 + j_l)*34];
    const ulonglong2* m2p = (const ulonglong2*)&sm.l.mask2[(2*16 + j_l)*34];
    const ulonglong2* m3p = (const ulonglong2*)&sm.l.mask2[(3*16 + j_l)*34];
    const uint2* xrow = (const uint2*)&sm.l.xb[b_l*34];
    const uint2* hrow = (const uint2*)&sm.l.hb[b_l*34];
    #pragma unroll
    for (int w2 = 0; w2 < 16; w2++){
      uint2 xv = xrow[w2], hv = hrow[w2];
      ulonglong2 a = m0p[w2];
      p0 += __popc(xv.x & (unsigned)a.x) + __popc(xv.y & (unsigned)a.y);
      n0 += __popc(xv.x & (unsigned)(a.x >> 32)) + __popc(xv.y & (unsigned)(a.y >> 32));
      ulonglong2 b = m1p[w2];
      p1 += __popc(xv.x & (unsigned)b.x) + __popc(xv.y & (unsigned)b.y);
      n1 += __popc(xv.x & (unsigned)(b.x >> 32)) + __popc(xv.y & (unsigned)(b.y >> 32));
      ulonglong2 c2 = m2p[w2];
      p2 += __popc(hv.x & (unsigned)c2.x) + __popc(hv.y & (unsigned)c2.y);
      n2 += __popc(hv.x & (unsigned)(c2.x >> 32)) + __popc(hv.y & (unsigned)(c2.y >> 32));
      ulonglong2 d = m3p[w2];
      p3 += __popc(hv.x & (unsigned)d.x) + __popc(hv.y & (unsigned)d.y);
      n3 += __popc(hv.x & (unsigned)(d.x >> 32)) + __popc(hv.y & (unsigned)(d.y >> 32));
    }
    const int g_if = sm.l.dl[0*16 + j_l] + p0 - n0;
    const int g_in = sm.l.dl[1*16 + j_l] + p1 - n1;
    const int g_hf = sm.l.dl[2*16 + j_l] + p2 - n2;
    const int g_hn = sm.l.dl[3*16 + j_l] + p3 - n3;

    // ---- FSU elementwise chain (exact, 2x-scaled ints)
    int s1 = g_if + g_hf;
    A1 = clampi(A1 + 2*s1 - 2049);                 // off_fg = 1024.5
    int fg_in = (A1 >= 2); A1 -= fg_in << 1;
    A2 = clampi(A2 + ((fg_in + 1) << 1));          // off 0, scale 2
    int fg = (A2 >= 4); A2 -= fg << 2;
    A3 = clampi(A3 + (g_hn << 1) - 1024);          // off 512
    int hnb = (A3 >= 2); A3 -= hnb << 1;

    sr1 = ((sr1 >> 1) | ((unsigned)hnb << 3)) & 0xFu;
    int ng_prod;
    {
      int cv = __popc(sr1) << 2;
      int bp = cv > sm.l.rngm[i1p & 15];
      int bi = cv > sm.l.rngm[i1i & 15];
      ng_prod = fg ? bp : (1 - bi);
      i1p += fg; i1i += 1 - fg;
    }
    A4 = clampi(A4 + (g_in << 1) - 1024);          // off 512
    int inb = (A4 >= 2); A4 -= inb << 1;
    A5 = clampi(A5 + ((inb + ng_prod) << 1) - 1);  // off 0.5
    int ng = (A5 >= 2); A5 -= ng << 1;

    sr2 = ((sr2 >> 1) | ((unsigned)ng << 3)) & 0xFu;
    int fgi;
    {
      int cv = __popc(sr2) << 2;
      int bp = cv > sm.l.rngm[i2p & 15];
      int bi = cv > sm.l.rngm[i2i & 15];
      fgi = (1 - fg) ? bp : (1 - bi);              // in0 = 1-fg
      i2p += 1 - fg; i2i += fg;
    }
    sr3 = ((sr3 >> 1) | ((unsigned)hcur << 3)) & 0xFu;
    int fgp;
    {
      int cv = __popc(sr3) << 2;
      int bp = cv > sm.l.rngm[i3p & 15];
      int bi = cv > sm.l.rngm[i3i & 15];
      fgp = fg ? bp : (1 - bi);                    // in0 = fg
      i3p += fg; i3i += 1 - fg;
    }
    A6 = clampi(A6 + ((ng + fgi + fgp) << 1) - 2); // off 1.0
    int hy = (A6 >= 2); A6 -= hy << 1;
    hcur = hy;

    if (t < 63){
      // publish h for step t+1: ONE tagged u64 atomic store per 32-bit chunk.
      // Tag rides in the same atomic word -> no ordering requirements at all.
      unsigned long long bal = __ballot(hy);
      if ((tid & 31) == 0){
        unsigned data = (unsigned)(bal >> (tid & 32));
        unsigned long long val = (unsigned long long)data
                               | ((unsigned long long)(unsigned)(t + 1) << 32);
        __hip_atomic_store(
            &hw[(((size_t)(par ^ 1)*4 + bg)*64 + jt)*16 + (tid >> 5)], val,
            __ATOMIC_RELAXED, __HIP_MEMORY_SCOPE_AGENT);
      }
    }
    out[(size_t)t*131072 + (size_t)bglob*1024 + j0 + j_l] = (float)hy;

    if (t < 63){
      __syncthreads();   // compute done -> LDS buffers safe to overwrite

      // prefetch next step's (immutable) masks/x/D into regs
      unsigned mreg[8], xreg[2];
      int dreg = 0;
      #pragma unroll
      for (int i = 0; i < 8; i++){
        int q = tid + i*NTHR;
        int r = q >> 6, qq = q & 63;
        int c = (r >> 4)*1024 + j0 + (r & 15);
        mreg[i] = msrc[((size_t)(t+1)*4096 + c)*64 + qq];
      }
      #pragma unroll
      for (int i = 0; i < 2; i++){
        int q = tid + i*NTHR;
        int bb = q >> 5, w = q & 31;
        xreg[i] = xp[((size_t)(t+1)*128 + b0 + bb)*32 + w];
      }
      if (tid < 64){
        int c = (tid >> 4)*1024 + j0 + (tid & 15);
        dreg = Dt[(t+1)*4096 + c];
      }

      // stage 1: wave 0 polls one representative slot per sibling jt
      const unsigned ep = (unsigned)(t + 1);
      if (tid < 64){
        const unsigned long long* slot =
            &hw[(((size_t)(par ^ 1)*4 + bg)*64 + tid)*16];
        while (true){
          unsigned long long v = __hip_atomic_load(slot, __ATOMIC_RELAXED,
                                                   __HIP_MEMORY_SCOPE_AGENT);
          if (__all((int)((unsigned)(v >> 32) >= ep))) break;
          __builtin_amdgcn_s_sleep(2);
        }
      }
      __syncthreads();   // S2

      // stage 2: pull-verify own 2 slots (self-validating tags) + commit regs
      #pragma unroll
      for (int i = 0; i < 2; i++){
        int q = tid + i*NTHR;       // q = jt*16 + bpair
        const unsigned long long* slot =
            &hw[((size_t)(par ^ 1)*4 + bg)*1024 + q];
        unsigned long long v;
        while (true){
          v = __hip_atomic_load(slot, __ATOMIC_RELAXED,
                                __HIP_MEMORY_SCOPE_AGENT);
          if ((unsigned)(v >> 32) >= ep) break;
          __builtin_amdgcn_s_sleep(1);
        }
        sm.l.hraw[(q >> 4)*17 + (q & 15)] = (unsigned)v;
      }
      #pragma unroll
      for (int i = 0; i < 8; i++){
        int q = tid + i*NTHR;
        int r = q >> 6, qq = q & 63;
        mlds[r*68 + qq] = mreg[i];
      }
      #pragma unroll
      for (int i = 0; i < 2; i++){
        int q = tid + i*NTHR;
        int bb = q >> 5, w = q & 31;
        sm.l.xb[bb*34 + w] = xreg[i];
      }
      if (tid < 64) sm.l.dl[tid] = dreg;
      __syncthreads();   // S3: hraw + LDS commits visible

      #pragma unroll
      for (int i = 0; i < 2; i++){
        int idx = tid + i*NTHR;
        int bb = idx >> 5, w = idx & 31;
        int rp = bb >> 1, sh = (bb & 1) << 4;
        unsigned lo = (sm.l.hraw[(2*w)*17 + rp] >> sh) & 0xFFFFu;
        unsigned hi = (sm.l.hraw[(2*w + 1)*17 + rp] >> sh) & 0xFFFFu;
        sm.l.hb[bb*34 + w] = lo | (hi << 16);
      }
      __syncthreads();   // S4: hb ready
    }
  }
}

extern "C" void kernel_launch(void* const* d_in, const int* in_sizes, int n_in,
                              void* d_out, int out_size, void* d_ws, size_t ws_size,
                              hipStream_t stream)
{
  (void)in_sizes; (void)n_in; (void)out_size; (void)ws_size;
  const float* x   = (const float*)d_in[0];
  const float* hx0 = (const float*)d_in[1];
  const float* wih = (const float*)d_in[2];
  const float* bih = (const float*)d_in[3];
  const float* whh = (const float*)d_in[4];
  const float* bhh = (const float*)d_in[5];
  float* out = (float*)d_out;
  unsigned char* ws = (unsigned char*)d_ws;

  // reset setup-barrier lines + tagged h-slot region every call (replay-safe:
  // stale/poisoned tags must never satisfy a poll)
  hipMemsetAsync(d_ws, 0, 4096, stream);
  hipMemsetAsync(ws + WS_HW, 0, 65536, stream);

  void* args[] = { (void*)&x, (void*)&hx0, (void*)&wih, (void*)&bih,
                   (void*)&whh, (void*)&bhh, (void*)&out, (void*)&ws };
  hipLaunchCooperativeKernel(reinterpret_cast<void*>(fsu_kernel),
                             dim3(NBLK), dim3(NTHR), args, 0, stream);
}

// Round 6
// 497.662 us; speedup vs baseline: 6.7344x; 1.0404x over previous
//
#include <hip/hip_runtime.h>

// FSU-MGU cell: exact integer reimplementation.
// Gate(b,c,t) = popc(bits_b & pos_{t,c}) - popc(bits_b & neg_{t,c}) + D_{t,c}
// pos: src>max(rp,ri), neg: src<=min(rp,ri), D = 1024 - #(src>ri) + (src_bias>rp).
// Main loop: fence-free tagged-slot exchange ({tag|data} in one u64 agent
// atomic). x-gate popc for step t+1 is computed BEFORE waiting on h(t+1) —
// only h-popc + FSU sit on the sequential critical path. 2 barriers/step.

#define NBLK 256
#define NTHR 512

// workspace layout (bytes); [0,4096) and hw region zeroed each call
#define WS_BAR_SUB   0u        // 8 counter lines, stride 128 (setup barrier)
#define WS_BAR_MST   1024u     // master counter (setup barrier)
#define WS_BAR_FLG   2048u     // 8 flag lines (setup barrier)
#define WS_RNGW   8192u
#define WS_RNGWI  9216u
#define WS_RNGM   10240u
#define WS_SRCB   12288u       // 4096 u16
#define WS_SRCW   20480u       // 4096*1024 u16 = 8,388,608 (end 8,409,088)
#define WS_XP     8409088u     // 64*128*32 u32 = 1,048,576 (end 9,457,664)
#define WS_HW     9457664u     // 2 region * 4 bg * 64 jt * 16 u64 = 65,536
#define WS_DT     9523200u     // 64*4096 i32 = 1,048,576 (end 10,571,776)
#define WS_MASKS  10571776u    // 64*4096*64 u32 = 67,108,864 (end 77,680,640)

struct SRng {
  unsigned mt[3][624];
  unsigned yb[3][624];
  unsigned draws[3][1248];
  int perm[3][256];
};
struct SC {
  unsigned short rows[16][1028];
  int rngw[64];
  int rngwi[64];
};
struct SL {
  unsigned long long mask2[2][64*34];  // double-buffered mask tiles
  unsigned xb[32*34];                  // x bits, row stride 34 u32
  unsigned short hrow16[32*68];        // h bits u16[row][jt'], stride 68
  int rngm[16];
};
union SU { SRng r; SC c; SL l; };

__device__ __forceinline__ unsigned mt_temper(unsigned y){
  y ^= y >> 11;
  y ^= (y << 7)  & 0x9d2c5680u;
  y ^= (y << 15) & 0xefc60000u;
  y ^= y >> 18;
  return y;
}

__device__ void mt_regen_serial(unsigned* mt){
  for (int i = 0; i < 624; i++){
    unsigned y = (mt[i] & 0x80000000u) | (mt[(i+1)%624] & 0x7fffffffu);
    mt[i] = mt[(i+397)%624] ^ (y >> 1) ^ ((y & 1u) ? 0x9908b0dfu : 0u);
  }
}

// numpy legacy RandomState: init_genrand seeding + Fisher-Yates with masked rejection.
__device__ void rng_gen(SU* sm, int* rngw, int* rngwi, int* rngm){
  const int tid = threadIdx.x;
  const int wv = tid >> 6, lane = tid & 63;
  const bool act = (wv < 3);
  if (act && lane == 0){
    unsigned* mt = sm->r.mt[wv];
    mt[0] = (unsigned)wv;  // seeds 0,1,2
    for (int i = 1; i < 624; i++)
      mt[i] = 1812433253u * (mt[i-1] ^ (mt[i-1] >> 30)) + (unsigned)i;
  }
  __syncthreads();
  for (int r = 0; r < 2; r++){
    if (act){
      unsigned* mt = sm->r.mt[wv]; unsigned* yb = sm->r.yb[wv];
      for (int i = lane; i < 623; i += 64)
        yb[i] = (mt[i] & 0x80000000u) | (mt[i+1] & 0x7fffffffu);
    }
    __syncthreads();
    if (act){
      unsigned* mt = sm->r.mt[wv]; unsigned* yb = sm->r.yb[wv];
      for (int i = lane; i < 227; i += 64){
        unsigned y = yb[i];
        mt[i] = mt[i+397] ^ (y >> 1) ^ ((y & 1u) ? 0x9908b0dfu : 0u);
      }
    }
    __syncthreads();
    if (act){
      unsigned* mt = sm->r.mt[wv]; unsigned* yb = sm->r.yb[wv];
      for (int i = 227 + lane; i < 454; i += 64){
        unsigned y = yb[i];
        mt[i] = mt[i-227] ^ (y >> 1) ^ ((y & 1u) ? 0x9908b0dfu : 0u);
      }
    }
    __syncthreads();
    if (act){
      unsigned* mt = sm->r.mt[wv]; unsigned* yb = sm->r.yb[wv];
      for (int i = 454 + lane; i < 624; i += 64){
        unsigned y = (i < 623) ? yb[i]
                   : ((mt[623] & 0x80000000u) | (mt[0] & 0x7fffffffu));
        mt[i] = mt[i-227] ^ (y >> 1) ^ ((y & 1u) ? 0x9908b0dfu : 0u);
      }
    }
    __syncthreads();
    if (act){
      unsigned* mt = sm->r.mt[wv];
      for (int i = lane; i < 624; i += 64)
        sm->r.draws[wv][r*624 + i] = mt_temper(mt[i]);
    }
    __syncthreads();
  }
  if (act && lane == 0){
    const int n = (wv == 2) ? 16 : 256;
    int* perm = sm->r.perm[wv];
    for (int i = 0; i < n; i++) perm[i] = i;
    int dp = 0, spos = 624;
    unsigned* mt = sm->r.mt[wv];
    for (int i = n - 1; i > 0; i--){
      unsigned mask = (unsigned)i;
      mask |= mask >> 1; mask |= mask >> 2; mask |= mask >> 4;
      mask |= mask >> 8; mask |= mask >> 16;
      unsigned v;
      do {
        unsigned d;
        if (dp < 1248) d = sm->r.draws[wv][dp++];
        else {
          if (spos >= 624){ mt_regen_serial(mt); spos = 0; }
          d = mt_temper(mt[spos++]);
        }
        v = d & mask;
      } while (v > (unsigned)i);
      int tmp = perm[i]; perm[i] = perm[v]; perm[v] = tmp;
    }
    int* dst = (wv == 0) ? rngw : (wv == 1) ? rngwi : rngm;
    for (int i = 0; i < n; i++) dst[i] = perm[i];
  }
}

// full-grid barrier WITH fences — setup phases only (publishes normal stores)
__device__ __forceinline__ void gbar_full(unsigned char* ws, unsigned ep){
  __syncthreads();
  if (threadIdx.x == 0){
    __threadfence();
    unsigned* sub = (unsigned*)(ws + WS_BAR_SUB + (blockIdx.x & 7)*128);
    unsigned old = atomicAdd(sub, 1u);
    if (old == ep*32u - 1u){
      unsigned* mst = (unsigned*)(ws + WS_BAR_MST);
      unsigned mo = atomicAdd(mst, 1u);
      if (mo == ep*8u - 1u){
        for (int i = 0; i < 8; i++)
          __hip_atomic_store((unsigned*)(ws + WS_BAR_FLG + i*128), ep,
                             __ATOMIC_RELAXED, __HIP_MEMORY_SCOPE_AGENT);
      }
    }
    const unsigned* fl = (const unsigned*)(ws + WS_BAR_FLG + (blockIdx.x & 7)*128);
    while (__hip_atomic_load(fl, __ATOMIC_RELAXED, __HIP_MEMORY_SCOPE_AGENT) < ep)
      __builtin_amdgcn_s_sleep(8);
  }
  __syncthreads();
  __threadfence();
}

__device__ __forceinline__ int clampi(int v){
  v = v < -512 ? -512 : v;
  v = v >  512 ?  512 : v;
  return v;
}

__global__ void __launch_bounds__(NTHR)
fsu_kernel(const float* __restrict__ x, const float* __restrict__ hx0,
           const float* __restrict__ wih, const float* __restrict__ bih,
           const float* __restrict__ whh, const float* __restrict__ bhh,
           float* __restrict__ out, unsigned char* __restrict__ ws)
{
  __shared__ SU sm;
  const int tid = threadIdx.x;
  const int bid = blockIdx.x;

  int* rngw  = (int*)(ws + WS_RNGW);
  int* rngwi = (int*)(ws + WS_RNGWI);
  int* rngm  = (int*)(ws + WS_RNGM);
  unsigned short* srcb = (unsigned short*)(ws + WS_SRCB);
  unsigned short* srcw = (unsigned short*)(ws + WS_SRCW);
  unsigned* xp   = (unsigned*)(ws + WS_XP);
  unsigned long long* hw = (unsigned long long*)(ws + WS_HW);
  int* Dt = (int*)(ws + WS_DT);
  unsigned long long* masks = (unsigned long long*)(ws + WS_MASKS);

  // ---------- phase 0: RNG tables (block 0) || bit-pack + src build (others)
  if (bid == 0){
    rng_gen(&sm, rngw, rngwi, rngm);
  } else {
    const int gtid = (bid - 1)*NTHR + tid;
    const int lane = tid & 63;
    const int gw = gtid >> 6;
    const int nw = (NBLK-1)*(NTHR/64);
    const int nthr = (NBLK-1)*NTHR;
    for (int ch = gw; ch < 131072; ch += nw){            // x bits
      float v = x[(size_t)ch*64 + lane];
      unsigned long long bal = __ballot(v != 0.0f);
      if ((lane & 31) == 0) xp[ch*2 + (lane >> 5)] = (unsigned)(bal >> lane);
    }
    for (int idx = gtid; idx < 4096; idx += nthr){       // initial h slots (region 0, tag 0)
      int bg2 = idx >> 10, jt2 = (idx >> 4) & 63, rp2 = idx & 15;
      int r0 = bg2*32 + 2*rp2;
      unsigned v = 0;
      for (int j = 0; j < 16; j++){
        v |= (hx0[(size_t)r0*1024 + jt2*16 + j] != 0.0f) ? (1u<<j) : 0u;
        v |= (hx0[(size_t)(r0+1)*1024 + jt2*16 + j] != 0.0f) ? (1u<<(16+j)) : 0u;
      }
      hw[idx] = (unsigned long long)v;  // tag 0; flushed by gbar_full fence
    }
    for (int idx = gtid; idx < 4096*1024; idx += nthr){  // src = round((clip+1)*128)
      int c = idx >> 10, k = idx & 1023;
      float wv2 = (c < 2048) ? wih[(size_t)c*1024 + k] : whh[(size_t)(c - 2048)*1024 + k];
      float cl = fminf(fmaxf(wv2, -1.0f), 1.0f);
      srcw[idx] = (unsigned short)(int)rintf((cl + 1.0f)*0.5f*256.0f);
    }
    for (int c = gtid; c < 4096; c += nthr){
      float bv = (c < 2048) ? bih[c] : bhh[c - 2048];
      float cl = fminf(fmaxf(bv, -1.0f), 1.0f);
      srcb[c] = (unsigned short)(int)rintf((cl + 1.0f)*0.5f*256.0f);
    }
  }
  gbar_full(ws, 1u);

  // ---------- phase C: pos/neg masks + D constants for all (t, col)
  {
    const int c0 = bid * 16;
    const unsigned* srcw32 = (const unsigned*)srcw;
    for (int q = tid; q < 16*512; q += NTHR){
      int r = q >> 9, w = q & 511;
      ((unsigned*)&sm.c.rows[r][0])[w] = srcw32[(size_t)(c0 + r)*512 + w];
    }
    if (tid < 64) sm.c.rngw[tid] = rngw[tid];
    if (tid >= 64 && tid < 128) sm.c.rngwi[tid - 64] = rngwi[tid - 64];
    __syncthreads();
    for (int rr = 0; rr < 2; rr++){
      int row = tid + rr*NTHR;            // 0..1023 : (t, local col)
      int t = row >> 4, lc = row & 15, col = c0 + lc;
      int rp = sm.c.rngw[t], ri = sm.c.rngwi[t];
      int hi = rp > ri ? rp : ri;
      int lo1 = (rp < ri ? rp : ri) + 1;
      bool rihi = (ri >= rp);
      const unsigned* srow = (const unsigned*)&sm.c.rows[lc][0];
      unsigned long long* gdst = masks + ((size_t)t*4096 + col)*32;
      int cnti = 0;
      for (int w = 0; w < 32; w++){
        unsigned pos = 0, neg = 0;
        #pragma unroll
        for (int i2 = 15; i2 >= 0; i2--){
          unsigned v2 = srow[w*16 + i2];
          int vH = (int)(v2 >> 16);
          int vL = (int)(v2 & 0xFFFFu);
          pos = (pos << 1) | ((unsigned)(hi - vH) >> 31);   // v > hi
          neg = (neg << 1) | ((unsigned)(vH - lo1) >> 31);  // v <= lo
          pos = (pos << 1) | ((unsigned)(hi - vL) >> 31);
          neg = (neg << 1) | ((unsigned)(vL - lo1) >> 31);
        }
        gdst[w] = (unsigned long long)pos | ((unsigned long long)neg << 32);
        cnti += rihi ? __popc(pos) : (32 - __popc(neg));    // count(src > ri)
      }
      Dt[t*4096 + col] = 1024 - cnti + (((int)srcb[col] > rp) ? 1 : 0);
    }
  }
  gbar_full(ws, 2u);

  // ---------- main recurrence
  // jt = bid & 63: the 4 bg-siblings of a jt land on the same XCD (bid%8 law)
  const int jt = bid & 63, bg = bid >> 6;
  const int j0 = jt * 16, b0 = bg * 32;
  const int b_l = tid >> 4, j_l = tid & 15;
  const int bglob = b0 + b_l;

  int hcur = (hx0[(size_t)bglob*1024 + j0 + j_l] != 0.0f) ? 1 : 0;
  int A1=0,A2=0,A3=0,A4=0,A5=0,A6=0;          // 2x-scaled accumulators
  unsigned sr1=10u, sr2=10u, sr3=10u;          // shift regs, init [0,1,0,1]
  int i1p=0,i1i=0,i2p=0,i2i=0,i3p=0,i3i=0;

  if (tid < 16) sm.l.rngm[tid] = rngm[tid];

  const unsigned* msrc = (const unsigned*)masks;
  int cur = 0;
  int xgf, xgn, dhf, dhn;       // x-gate totals (incl D) + h-gate D, for step t
  unsigned mreg[8], xreg[2];    // prefetch pipeline (step t+1 tile)
  int dreg[4];

  // ---- prime: stage t=0 into buf0, initial h, x-popc(0), prefetch t=1
  {
    unsigned* mbuf = (unsigned*)sm.l.mask2[0];
    #pragma unroll
    for (int i = 0; i < 8; i++){
      int q = tid + i*NTHR;
      int r = q >> 6, qq = q & 63;
      int c = (r >> 4)*1024 + j0 + (r & 15);
      mbuf[r*68 + qq] = msrc[((size_t)0*4096 + c)*64 + qq];
    }
    #pragma unroll
    for (int i = 0; i < 2; i++){
      int q = tid + i*NTHR;
      int bb = q >> 5, w = q & 31;
      sm.l.xb[bb*34 + w] = xp[((size_t)0*128 + b0 + bb)*32 + w];
    }
    #pragma unroll
    for (int i = 0; i < 2; i++){
      int q = tid + i*NTHR;          // region 0 slots (setup-initialized)
      unsigned long long v = __hip_atomic_load(&hw[(size_t)bg*1024 + q],
                                               __ATOMIC_RELAXED,
                                               __HIP_MEMORY_SCOPE_AGENT);
      int jt_ = q >> 4, rp_ = q & 15;
      unsigned data = (unsigned)v;
      sm.l.hrow16[(2*rp_)*68 + jt_]   = (unsigned short)(data & 0xFFFFu);
      sm.l.hrow16[(2*rp_+1)*68 + jt_] = (unsigned short)(data >> 16);
    }
    int d0[4];
    #pragma unroll
    for (int g = 0; g < 4; g++) d0[g] = Dt[0*4096 + g*1024 + j0 + j_l];
    __syncthreads();
    // x-popc for t=0 from buf0
    int p0=0,n0=0,p1=0,n1=0;
    const uint2* xrow = (const uint2*)&sm.l.xb[b_l*34];
    const ulonglong2* m0p = (const ulonglong2*)&sm.l.mask2[0][(0  + j_l)*34];
    const ulonglong2* m1p = (const ulonglong2*)&sm.l.mask2[0][(16 + j_l)*34];
    #pragma unroll
    for (int w2 = 0; w2 < 16; w2++){
      uint2 xv = xrow[w2];
      ulonglong2 a = m0p[w2];
      p0 += __popc(xv.x & (unsigned)a.x) + __popc(xv.y & (unsigned)a.y);
      n0 += __popc(xv.x & (unsigned)(a.x >> 32)) + __popc(xv.y & (unsigned)(a.y >> 32));
      ulonglong2 b = m1p[w2];
      p1 += __popc(xv.x & (unsigned)b.x) + __popc(xv.y & (unsigned)b.y);
      n1 += __popc(xv.x & (unsigned)(b.x >> 32)) + __popc(xv.y & (unsigned)(b.y >> 32));
    }
    xgf = d0[0] + p0 - n0;
    xgn = d0[1] + p1 - n1;
    dhf = d0[2]; dhn = d0[3];
    // prefetch tile t=1
    #pragma unroll
    for (int i = 0; i < 8; i++){
      int q = tid + i*NTHR;
      int r = q >> 6, qq = q & 63;
      int c = (r >> 4)*1024 + j0 + (r & 15);
      mreg[i] = msrc[((size_t)1*4096 + c)*64 + qq];
    }
    #pragma unroll
    for (int i = 0; i < 2; i++){
      int q = tid + i*NTHR;
      int bb = q >> 5, w = q & 31;
      xreg[i] = xp[((size_t)1*128 + b0 + bb)*32 + w];
    }
    #pragma unroll
    for (int g = 0; g < 4; g++) dreg[g] = Dt[1*4096 + g*1024 + j0 + j_l];
  }

  for (int t = 0; t < 64; t++){
    const int par = t & 1;

    // ---- h-gate popc (the only gate work on the sequential path)
    int p2=0,n2=0,p3=0,n3=0;
    {
      const uint2* hrow = (const uint2*)&sm.l.hrow16[b_l*68];
      const ulonglong2* m2p = (const ulonglong2*)&sm.l.mask2[cur][(32 + j_l)*34];
      const ulonglong2* m3p = (const ulonglong2*)&sm.l.mask2[cur][(48 + j_l)*34];
      #pragma unroll
      for (int w2 = 0; w2 < 16; w2++){
        uint2 hv = hrow[w2];
        ulonglong2 c2 = m2p[w2];
        p2 += __popc(hv.x & (unsigned)c2.x) + __popc(hv.y & (unsigned)c2.y);
        n2 += __popc(hv.x & (unsigned)(c2.x >> 32)) + __popc(hv.y & (unsigned)(c2.y >> 32));
        ulonglong2 d = m3p[w2];
        p3 += __popc(hv.x & (unsigned)d.x) + __popc(hv.y & (unsigned)d.y);
        n3 += __popc(hv.x & (unsigned)(d.x >> 32)) + __popc(hv.y & (unsigned)(d.y >> 32));
      }
    }
    const int g_hf = dhf + p2 - n2;
    const int g_hn = dhn + p3 - n3;

    // ---- FSU elementwise chain (exact, 2x-scaled ints)
    int s1 = xgf + g_hf;
    A1 = clampi(A1 + 2*s1 - 2049);                 // off_fg = 1024.5
    int fg_in = (A1 >= 2); A1 -= fg_in << 1;
    A2 = clampi(A2 + ((fg_in + 1) << 1));          // off 0, scale 2
    int fg = (A2 >= 4); A2 -= fg << 2;
    A3 = clampi(A3 + (g_hn << 1) - 1024);          // off 512
    int hnb = (A3 >= 2); A3 -= hnb << 1;

    sr1 = ((sr1 >> 1) | ((unsigned)hnb << 3)) & 0xFu;
    int ng_prod;
    {
      int cv = __popc(sr1) << 2;
      int bp = cv > sm.l.rngm[i1p & 15];
      int bi = cv > sm.l.rngm[i1i & 15];
      ng_prod = fg ? bp : (1 - bi);
      i1p += fg; i1i += 1 - fg;
    }
    A4 = clampi(A4 + (xgn << 1) - 1024);           // off 512
    int inb = (A4 >= 2); A4 -= inb << 1;
    A5 = clampi(A5 + ((inb + ng_prod) << 1) - 1);  // off 0.5
    int ng = (A5 >= 2); A5 -= ng << 1;

    sr2 = ((sr2 >> 1) | ((unsigned)ng << 3)) & 0xFu;
    int fgi;
    {
      int cv = __popc(sr2) << 2;
      int bp = cv > sm.l.rngm[i2p & 15];
      int bi = cv > sm.l.rngm[i2i & 15];
      fgi = (1 - fg) ? bp : (1 - bi);              // in0 = 1-fg
      i2p += 1 - fg; i2i += fg;
    }
    sr3 = ((sr3 >> 1) | ((unsigned)hcur << 3)) & 0xFu;
    int fgp;
    {
      int cv = __popc(sr3) << 2;
      int bp = cv > sm.l.rngm[i3p & 15];
      int bi = cv > sm.l.rngm[i3i & 15];
      fgp = fg ? bp : (1 - bi);                    // in0 = fg
      i3p += fg; i3i += 1 - fg;
    }
    A6 = clampi(A6 + ((ng + fgi + fgp) << 1) - 2); // off 1.0
    int hy = (A6 >= 2); A6 -= hy << 1;
    hcur = hy;

    if (t < 63){
      // publish ASAP: one tagged u64 agent store per 32-bit h chunk
      unsigned long long bal = __ballot(hy);
      if ((tid & 31) == 0){
        unsigned data = (unsigned)(bal >> (tid & 32));
        unsigned long long val = (unsigned long long)data
                               | ((unsigned long long)(unsigned)(t + 1) << 32);
        __hip_atomic_store(
            &hw[(((size_t)((par ^ 1)*4 + bg))*64 + jt)*16 + (tid >> 5)], val,
            __ATOMIC_RELAXED, __HIP_MEMORY_SCOPE_AGENT);
      }
    }
    out[(size_t)t*131072 + (size_t)bglob*1024 + j0 + j_l] = (float)hy;

    if (t < 63){
      // commit prefetched t+1 tile into the OTHER mask buffer + xb
      {
        unsigned* mbuf = (unsigned*)sm.l.mask2[cur ^ 1];
        #pragma unroll
        for (int i = 0; i < 8; i++){
          int q = tid + i*NTHR;
          int r = q >> 6, qq = q & 63;
          mbuf[r*68 + qq] = mreg[i];
        }
        #pragma unroll
        for (int i = 0; i < 2; i++){
          int q = tid + i*NTHR;
          int bb = q >> 5, w = q & 31;
          sm.l.xb[bb*34 + w] = xreg[i];
        }
      }
      __syncthreads();   // B1: t+1 masks/x visible; all h-popc(t) reads done

      // x-popc for t+1 — overlaps sibling publish propagation
      {
        int p0=0,n0=0,p1=0,n1=0;
        const uint2* xrow = (const uint2*)&sm.l.xb[b_l*34];
        const ulonglong2* m0p = (const ulonglong2*)&sm.l.mask2[cur ^ 1][(0  + j_l)*34];
        const ulonglong2* m1p = (const ulonglong2*)&sm.l.mask2[cur ^ 1][(16 + j_l)*34];
        #pragma unroll
        for (int w2 = 0; w2 < 16; w2++){
          uint2 xv = xrow[w2];
          ulonglong2 a = m0p[w2];
          p0 += __popc(xv.x & (unsigned)a.x) + __popc(xv.y & (unsigned)a.y);
          n0 += __popc(xv.x & (unsigned)(a.x >> 32)) + __popc(xv.y & (unsigned)(a.y >> 32));
          ulonglong2 b = m1p[w2];
          p1 += __popc(xv.x & (unsigned)b.x) + __popc(xv.y & (unsigned)b.y);
          n1 += __popc(xv.x & (unsigned)(b.x >> 32)) + __popc(xv.y & (unsigned)(b.y >> 32));
        }
        xgf = dreg[0] + p0 - n0;
        xgn = dreg[1] + p1 - n1;
        dhf = dreg[2]; dhn = dreg[3];
      }

      // issue prefetch for tile t+2 (completes under the h wait)
      if (t < 62){
        #pragma unroll
        for (int i = 0; i < 8; i++){
          int q = tid + i*NTHR;
          int r = q >> 6, qq = q & 63;
          int c = (r >> 4)*1024 + j0 + (r & 15);
          mreg[i] = msrc[((size_t)(t+2)*4096 + c)*64 + qq];
        }
        #pragma unroll
        for (int i = 0; i < 2; i++){
          int q = tid + i*NTHR;
          int bb = q >> 5, w = q & 31;
          xreg[i] = xp[((size_t)(t+2)*128 + b0 + bb)*32 + w];
        }
        #pragma unroll
        for (int g = 0; g < 4; g++)
          dreg[g] = Dt[(t+2)*4096 + g*1024 + j0 + j_l];
      }

      // direct per-thread tag-spin pull of h(t+1) (2 slots each)
      {
        const unsigned ep = (unsigned)(t + 1);
        #pragma unroll
        for (int i = 0; i < 2; i++){
          int q = tid + i*NTHR;
          const unsigned long long* slot =
              &hw[((size_t)((par ^ 1)*4 + bg))*1024 + q];
          unsigned long long v = __hip_atomic_load(slot, __ATOMIC_RELAXED,
                                                   __HIP_MEMORY_SCOPE_AGENT);
          while ((unsigned)(v >> 32) < ep){
            __builtin_amdgcn_s_sleep(1);
            v = __hip_atomic_load(slot, __ATOMIC_RELAXED,
                                  __HIP_MEMORY_SCOPE_AGENT);
          }
          int jt_ = q >> 4, rp_ = q & 15;
          unsigned data = (unsigned)v;
          sm.l.hrow16[(2*rp_)*68 + jt_]   = (unsigned short)(data & 0xFFFFu);
          sm.l.hrow16[(2*rp_+1)*68 + jt_] = (unsigned short)(data >> 16);
        }
      }
      __syncthreads();   // B2: fresh h in LDS
      cur ^= 1;
    }
  }
}

extern "C" void kernel_launch(void* const* d_in, const int* in_sizes, int n_in,
                              void* d_out, int out_size, void* d_ws, size_t ws_size,
                              hipStream_t stream)
{
  (void)in_sizes; (void)n_in; (void)out_size; (void)ws_size;
  const float* x   = (const float*)d_in[0];
  const float* hx0 = (const float*)d_in[1];
  const float* wih = (const float*)d_in[2];
  const float* bih = (const float*)d_in[3];
  const float* whh = (const float*)d_in[4];
  const float* bhh = (const float*)d_in[5];
  float* out = (float*)d_out;
  unsigned char* ws = (unsigned char*)d_ws;

  // reset setup-barrier lines + tagged h-slot region every call (replay-safe:
  // stale/poisoned tags must never satisfy a poll)
  hipMemsetAsync(d_ws, 0, 4096, stream);
  hipMemsetAsync(ws + WS_HW, 0, 65536, stream);

  void* args[] = { (void*)&x, (void*)&hx0, (void*)&wih, (void*)&bih,
                   (void*)&whh, (void*)&bhh, (void*)&out, (void*)&ws };
  hipLaunchCooperativeKernel(reinterpret_cast<void*>(fsu_kernel),
                             dim3(NBLK), dim3(NTHR), args, 0, stream);
}

// Round 7
// 481.201 us; speedup vs baseline: 6.9648x; 1.0342x over previous
//
#include <hip/hip_runtime.h>

// FSU-MGU cell: exact integer reimplementation.
// Gate(b,c,t) = sum_w popc( (bits_w & pos_w) | (~bits_w & neg_w) ) + D'(t,c)
//   (v_bfi_b32 form; pos/neg disjoint; D' folds 1024-#(src>ri)+(bias>rp)-#neg)
// 1024 threads/block: lanes l and l^32 split the K-words of one output and
// combine via __shfl_xor(.,32); FSU runs duplicated on both lanes (identical
// state). 2 barriers/step; fence-free tagged-slot h exchange ({tag|data} u64).

#define NBLK 256
#define NTHR 1024

// workspace layout (bytes); [0,4096) and hw region zeroed each call
#define WS_BAR_SUB   0u        // 8 counter lines, stride 128 (setup barrier)
#define WS_BAR_MST   1024u     // master counter (setup barrier)
#define WS_BAR_FLG   2048u     // 8 flag lines (setup barrier)
#define WS_RNGW   8192u
#define WS_RNGWI  9216u
#define WS_RNGM   10240u
#define WS_SRCB   12288u       // 4096 u16
#define WS_SRCW   20480u       // 4096*1024 u16 = 8,388,608 (end 8,409,088)
#define WS_XP     8409088u     // 64*128*32 u32 = 1,048,576 (end 9,457,664)
#define WS_HW     9457664u     // 2 region * 4 bg * 64 jt * 16 u64 = 65,536
#define WS_DT     9523200u     // 64*4096 i32 = 1,048,576 (end 10,571,776)
#define WS_MASKS  10571776u    // 64*4096*64 u32 = 67,108,864 (end 77,680,640)

struct SRng {
  unsigned mt[3][624];
  unsigned yb[3][624];
  unsigned draws[3][1248];
  int perm[3][256];
};
struct SC {
  unsigned short rows[16][1028];
  int rngw[64];
  int rngwi[64];
};
struct SL {
  unsigned long long mask2[2][64*34];  // double-buffered mask tiles
  unsigned xb[32*34];                  // x bits, row stride 34 u32
  unsigned short hrow16[32*68];        // h bits u16[row][jt'], stride 68
  int rngm[16];
};
union SU { SRng r; SC c; SL l; };

__device__ __forceinline__ unsigned mt_temper(unsigned y){
  y ^= y >> 11;
  y ^= (y << 7)  & 0x9d2c5680u;
  y ^= (y << 15) & 0xefc60000u;
  y ^= y >> 18;
  return y;
}

__device__ void mt_regen_serial(unsigned* mt){
  for (int i = 0; i < 624; i++){
    unsigned y = (mt[i] & 0x80000000u) | (mt[(i+1)%624] & 0x7fffffffu);
    mt[i] = mt[(i+397)%624] ^ (y >> 1) ^ ((y & 1u) ? 0x9908b0dfu : 0u);
  }
}

// numpy legacy RandomState: init_genrand seeding + Fisher-Yates with masked rejection.
__device__ void rng_gen(SU* sm, int* rngw, int* rngwi, int* rngm){
  const int tid = threadIdx.x;
  const int wv = tid >> 6, lane = tid & 63;
  const bool act = (wv < 3);
  if (act && lane == 0){
    unsigned* mt = sm->r.mt[wv];
    mt[0] = (unsigned)wv;  // seeds 0,1,2
    for (int i = 1; i < 624; i++)
      mt[i] = 1812433253u * (mt[i-1] ^ (mt[i-1] >> 30)) + (unsigned)i;
  }
  __syncthreads();
  for (int r = 0; r < 2; r++){
    if (act){
      unsigned* mt = sm->r.mt[wv]; unsigned* yb = sm->r.yb[wv];
      for (int i = lane; i < 623; i += 64)
        yb[i] = (mt[i] & 0x80000000u) | (mt[i+1] & 0x7fffffffu);
    }
    __syncthreads();
    if (act){
      unsigned* mt = sm->r.mt[wv]; unsigned* yb = sm->r.yb[wv];
      for (int i = lane; i < 227; i += 64){
        unsigned y = yb[i];
        mt[i] = mt[i+397] ^ (y >> 1) ^ ((y & 1u) ? 0x9908b0dfu : 0u);
      }
    }
    __syncthreads();
    if (act){
      unsigned* mt = sm->r.mt[wv]; unsigned* yb = sm->r.yb[wv];
      for (int i = 227 + lane; i < 454; i += 64){
        unsigned y = yb[i];
        mt[i] = mt[i-227] ^ (y >> 1) ^ ((y & 1u) ? 0x9908b0dfu : 0u);
      }
    }
    __syncthreads();
    if (act){
      unsigned* mt = sm->r.mt[wv]; unsigned* yb = sm->r.yb[wv];
      for (int i = 454 + lane; i < 624; i += 64){
        unsigned y = (i < 623) ? yb[i]
                   : ((mt[623] & 0x80000000u) | (mt[0] & 0x7fffffffu));
        mt[i] = mt[i-227] ^ (y >> 1) ^ ((y & 1u) ? 0x9908b0dfu : 0u);
      }
    }
    __syncthreads();
    if (act){
      unsigned* mt = sm->r.mt[wv];
      for (int i = lane; i < 624; i += 64)
        sm->r.draws[wv][r*624 + i] = mt_temper(mt[i]);
    }
    __syncthreads();
  }
  if (act && lane == 0){
    const int n = (wv == 2) ? 16 : 256;
    int* perm = sm->r.perm[wv];
    for (int i = 0; i < n; i++) perm[i] = i;
    int dp = 0, spos = 624;
    unsigned* mt = sm->r.mt[wv];
    for (int i = n - 1; i > 0; i--){
      unsigned mask = (unsigned)i;
      mask |= mask >> 1; mask |= mask >> 2; mask |= mask >> 4;
      mask |= mask >> 8; mask |= mask >> 16;
      unsigned v;
      do {
        unsigned d;
        if (dp < 1248) d = sm->r.draws[wv][dp++];
        else {
          if (spos >= 624){ mt_regen_serial(mt); spos = 0; }
          d = mt_temper(mt[spos++]);
        }
        v = d & mask;
      } while (v > (unsigned)i);
      int tmp = perm[i]; perm[i] = perm[v]; perm[v] = tmp;
    }
    int* dst = (wv == 0) ? rngw : (wv == 1) ? rngwi : rngm;
    for (int i = 0; i < n; i++) dst[i] = perm[i];
  }
}

// full-grid barrier WITH fences — setup phases only (publishes normal stores)
__device__ __forceinline__ void gbar_full(unsigned char* ws, unsigned ep){
  __syncthreads();
  if (threadIdx.x == 0){
    __threadfence();
    unsigned* sub = (unsigned*)(ws + WS_BAR_SUB + (blockIdx.x & 7)*128);
    unsigned old = atomicAdd(sub, 1u);
    if (old == ep*32u - 1u){
      unsigned* mst = (unsigned*)(ws + WS_BAR_MST);
      unsigned mo = atomicAdd(mst, 1u);
      if (mo == ep*8u - 1u){
        for (int i = 0; i < 8; i++)
          __hip_atomic_store((unsigned*)(ws + WS_BAR_FLG + i*128), ep,
                             __ATOMIC_RELAXED, __HIP_MEMORY_SCOPE_AGENT);
      }
    }
    const unsigned* fl = (const unsigned*)(ws + WS_BAR_FLG + (blockIdx.x & 7)*128);
    while (__hip_atomic_load(fl, __ATOMIC_RELAXED, __HIP_MEMORY_SCOPE_AGENT) < ep)
      __builtin_amdgcn_s_sleep(8);
  }
  __syncthreads();
  __threadfence();
}

__device__ __forceinline__ int clampi(int v){
  v = v < -512 ? -512 : v;
  v = v >  512 ?  512 : v;
  return v;
}

// (x & p) | (~x & n)  ->  v_bfi_b32
__device__ __forceinline__ unsigned bfi(unsigned x, unsigned p, unsigned n){
  return (x & p) | (~x & n);
}

__global__ void __launch_bounds__(NTHR)
fsu_kernel(const float* __restrict__ x, const float* __restrict__ hx0,
           const float* __restrict__ wih, const float* __restrict__ bih,
           const float* __restrict__ whh, const float* __restrict__ bhh,
           float* __restrict__ out, unsigned char* __restrict__ ws)
{
  __shared__ SU sm;
  const int tid = threadIdx.x;
  const int bid = blockIdx.x;

  int* rngw  = (int*)(ws + WS_RNGW);
  int* rngwi = (int*)(ws + WS_RNGWI);
  int* rngm  = (int*)(ws + WS_RNGM);
  unsigned short* srcb = (unsigned short*)(ws + WS_SRCB);
  unsigned short* srcw = (unsigned short*)(ws + WS_SRCW);
  unsigned* xp   = (unsigned*)(ws + WS_XP);
  unsigned long long* hw = (unsigned long long*)(ws + WS_HW);
  int* Dt = (int*)(ws + WS_DT);
  unsigned long long* masks = (unsigned long long*)(ws + WS_MASKS);

  // ---------- phase 0: RNG tables (block 0) || bit-pack + src build (others)
  if (bid == 0){
    rng_gen(&sm, rngw, rngwi, rngm);
  } else {
    const int gtid = (bid - 1)*NTHR + tid;
    const int lane = tid & 63;
    const int gw = gtid >> 6;
    const int nw = (NBLK-1)*(NTHR/64);
    const int nthr = (NBLK-1)*NTHR;
    for (int ch = gw; ch < 131072; ch += nw){            // x bits
      float v = x[(size_t)ch*64 + lane];
      unsigned long long bal = __ballot(v != 0.0f);
      if ((lane & 31) == 0) xp[ch*2 + (lane >> 5)] = (unsigned)(bal >> lane);
    }
    for (int idx = gtid; idx < 4096; idx += nthr){       // initial h slots (region 0, tag 0)
      int bg2 = idx >> 10, jt2 = (idx >> 4) & 63, rp2 = idx & 15;
      int r0 = bg2*32 + 2*rp2;
      unsigned v = 0;
      for (int j = 0; j < 16; j++){
        v |= (hx0[(size_t)r0*1024 + jt2*16 + j] != 0.0f) ? (1u<<j) : 0u;
        v |= (hx0[(size_t)(r0+1)*1024 + jt2*16 + j] != 0.0f) ? (1u<<(16+j)) : 0u;
      }
      hw[idx] = (unsigned long long)v;  // tag 0; flushed by gbar_full fence
    }
    for (int idx = gtid; idx < 4096*1024; idx += nthr){  // src = round((clip+1)*128)
      int c = idx >> 10, k = idx & 1023;
      float wv2 = (c < 2048) ? wih[(size_t)c*1024 + k] : whh[(size_t)(c - 2048)*1024 + k];
      float cl = fminf(fmaxf(wv2, -1.0f), 1.0f);
      srcw[idx] = (unsigned short)(int)rintf((cl + 1.0f)*0.5f*256.0f);
    }
    for (int c = gtid; c < 4096; c += nthr){
      float bv = (c < 2048) ? bih[c] : bhh[c - 2048];
      float cl = fminf(fmaxf(bv, -1.0f), 1.0f);
      srcb[c] = (unsigned short)(int)rintf((cl + 1.0f)*0.5f*256.0f);
    }
  }
  gbar_full(ws, 1u);

  // ---------- phase C: pos/neg masks + D' constants (popc(neg) folded in)
  {
    const int c0 = bid * 16;
    const unsigned* srcw32 = (const unsigned*)srcw;
    for (int q = tid; q < 16*512; q += NTHR){
      int r = q >> 9, w = q & 511;
      ((unsigned*)&sm.c.rows[r][0])[w] = srcw32[(size_t)(c0 + r)*512 + w];
    }
    if (tid < 64) sm.c.rngw[tid] = rngw[tid];
    if (tid >= 64 && tid < 128) sm.c.rngwi[tid - 64] = rngwi[tid - 64];
    __syncthreads();
    for (int row = tid; row < 1024; row += NTHR){   // (t, local col)
      int t = row >> 4, lc = row & 15, col = c0 + lc;
      int rp = sm.c.rngw[t], ri = sm.c.rngwi[t];
      int hi = rp > ri ? rp : ri;
      int lo1 = (rp < ri ? rp : ri) + 1;
      bool rihi = (ri >= rp);
      const unsigned* srow = (const unsigned*)&sm.c.rows[lc][0];
      unsigned long long* gdst = masks + ((size_t)t*4096 + col)*32;
      int cnti = 0, cntn = 0;
      for (int w = 0; w < 32; w++){
        unsigned pos = 0, neg = 0;
        #pragma unroll
        for (int i2 = 15; i2 >= 0; i2--){
          unsigned v2 = srow[w*16 + i2];
          int vH = (int)(v2 >> 16);
          int vL = (int)(v2 & 0xFFFFu);
          pos = (pos << 1) | ((unsigned)(hi - vH) >> 31);   // v > hi
          neg = (neg << 1) | ((unsigned)(vH - lo1) >> 31);  // v <= lo
          pos = (pos << 1) | ((unsigned)(hi - vL) >> 31);
          neg = (neg << 1) | ((unsigned)(vL - lo1) >> 31);
        }
        gdst[w] = (unsigned long long)pos | ((unsigned long long)neg << 32);
        cnti += rihi ? __popc(pos) : (32 - __popc(neg));    // count(src > ri)
        cntn += __popc(neg);
      }
      Dt[t*4096 + col] = 1024 - cnti - cntn + (((int)srcb[col] > rp) ? 1 : 0);
    }
  }
  gbar_full(ws, 2u);

  // ---------- main recurrence
  // jt = bid & 63: the 4 bg-siblings of a jt land on the same XCD (bid%8 law)
  const int jt = bid & 63, bg = bid >> 6;
  const int j0 = jt * 16, b0 = bg * 32;
  // intra-wave K-split: lanes l and l^32 share output o, each does 8 of 16 w2
  const int kh  = (tid >> 5) & 1;
  const int o   = ((tid >> 6) << 5) + (tid & 31);   // 0..511
  const int b_l = o >> 4, j_l = o & 15;
  const int bglob = b0 + b_l;
  const int w2lo = kh << 3;

  int hcur = (hx0[(size_t)bglob*1024 + j0 + j_l] != 0.0f) ? 1 : 0;
  int A1=0,A2=0,A3=0,A4=0,A5=0,A6=0;          // 2x-scaled accumulators
  unsigned sr1=10u, sr2=10u, sr3=10u;          // shift regs, init [0,1,0,1]
  int i1p=0,i1i=0,i2p=0,i2i=0,i3p=0,i3i=0;

  if (tid < 16) sm.l.rngm[tid] = rngm[tid];

  const unsigned* msrc = (const unsigned*)masks;
  int cur = 0;
  int xgf, xgn, dhf, dhn;       // x-gate totals (incl D') + h-gate D', step t
  unsigned mreg[4], xreg;       // prefetch pipeline (next tile)
  int dreg[4];

  // ---- prime: stage t=0, initial h, x-popc(0), prefetch t=1
  {
    unsigned* mbuf = (unsigned*)sm.l.mask2[0];
    #pragma unroll
    for (int i = 0; i < 4; i++){
      int q = tid + i*NTHR;
      int r = q >> 6, qq = q & 63;
      int c = (r >> 4)*1024 + j0 + (r & 15);
      mbuf[r*68 + qq] = msrc[((size_t)0*4096 + c)*64 + qq];
    }
    {
      int bb = tid >> 5, w = tid & 31;
      sm.l.xb[bb*34 + w] = xp[((size_t)0*128 + b0 + bb)*32 + w];
    }
    {
      unsigned long long v = __hip_atomic_load(&hw[(size_t)bg*1024 + tid],
                                               __ATOMIC_RELAXED,
                                               __HIP_MEMORY_SCOPE_AGENT);
      int jt_ = tid >> 4, rp_ = tid & 15;
      unsigned data = (unsigned)v;
      sm.l.hrow16[(2*rp_)*68 + jt_]   = (unsigned short)(data & 0xFFFFu);
      sm.l.hrow16[(2*rp_+1)*68 + jt_] = (unsigned short)(data >> 16);
    }
    #pragma unroll
    for (int g = 0; g < 4; g++) dreg[g] = Dt[0*4096 + g*1024 + j0 + j_l];
    __syncthreads();
    // x-popc for t=0 (half-K each, combine via shfl_xor 32)
    int s0=0, s1=0;
    const uint2* xrow = (const uint2*)&sm.l.xb[b_l*34];
    const ulonglong2* m0p = (const ulonglong2*)&sm.l.mask2[0][(0  + j_l)*34];
    const ulonglong2* m1p = (const ulonglong2*)&sm.l.mask2[0][(16 + j_l)*34];
    #pragma unroll
    for (int w2i = 0; w2i < 8; w2i++){
      int w2 = w2lo + w2i;
      uint2 xv = xrow[w2];
      ulonglong2 a = m0p[w2];
      s0 += __popc(bfi(xv.x, (unsigned)a.x, (unsigned)(a.x >> 32)));
      s0 += __popc(bfi(xv.y, (unsigned)a.y, (unsigned)(a.y >> 32)));
      ulonglong2 b = m1p[w2];
      s1 += __popc(bfi(xv.x, (unsigned)b.x, (unsigned)(b.x >> 32)));
      s1 += __popc(bfi(xv.y, (unsigned)b.y, (unsigned)(b.y >> 32)));
    }
    s0 += __shfl_xor(s0, 32);
    s1 += __shfl_xor(s1, 32);
    xgf = dreg[0] + s0;
    xgn = dreg[1] + s1;
    dhf = dreg[2]; dhn = dreg[3];
    // prefetch tile t=1
    #pragma unroll
    for (int i = 0; i < 4; i++){
      int q = tid + i*NTHR;
      int r = q >> 6, qq = q & 63;
      int c = (r >> 4)*1024 + j0 + (r & 15);
      mreg[i] = msrc[((size_t)1*4096 + c)*64 + qq];
    }
    {
      int bb = tid >> 5, w = tid & 31;
      xreg = xp[((size_t)1*128 + b0 + bb)*32 + w];
    }
    #pragma unroll
    for (int g = 0; g < 4; g++) dreg[g] = Dt[1*4096 + g*1024 + j0 + j_l];
  }

  for (int t = 0; t < 64; t++){
    const int par = t & 1;

    // ---- h-gate popc (half-K, bfi form) + wave-local combine
    int s2=0, s3=0;
    {
      const uint2* hrow = (const uint2*)&sm.l.hrow16[b_l*68];
      const ulonglong2* m2p = (const ulonglong2*)&sm.l.mask2[cur][(32 + j_l)*34];
      const ulonglong2* m3p = (const ulonglong2*)&sm.l.mask2[cur][(48 + j_l)*34];
      #pragma unroll
      for (int w2i = 0; w2i < 8; w2i++){
        int w2 = w2lo + w2i;
        uint2 hv = hrow[w2];
        ulonglong2 c2 = m2p[w2];
        s2 += __popc(bfi(hv.x, (unsigned)c2.x, (unsigned)(c2.x >> 32)));
        s2 += __popc(bfi(hv.y, (unsigned)c2.y, (unsigned)(c2.y >> 32)));
        ulonglong2 d = m3p[w2];
        s3 += __popc(bfi(hv.x, (unsigned)d.x, (unsigned)(d.x >> 32)));
        s3 += __popc(bfi(hv.y, (unsigned)d.y, (unsigned)(d.y >> 32)));
      }
    }
    s2 += __shfl_xor(s2, 32);
    s3 += __shfl_xor(s3, 32);
    const int g_hf = dhf + s2;
    const int g_hn = dhn + s3;

    // ---- FSU elementwise chain (exact, 2x-scaled ints; duplicated on l, l^32)
    int s1v = xgf + g_hf;
    A1 = clampi(A1 + 2*s1v - 2049);                // off_fg = 1024.5
    int fg_in = (A1 >= 2); A1 -= fg_in << 1;
    A2 = clampi(A2 + ((fg_in + 1) << 1));          // off 0, scale 2
    int fg = (A2 >= 4); A2 -= fg << 2;
    A3 = clampi(A3 + (g_hn << 1) - 1024);          // off 512
    int hnb = (A3 >= 2); A3 -= hnb << 1;

    sr1 = ((sr1 >> 1) | ((unsigned)hnb << 3)) & 0xFu;
    int ng_prod;
    {
      int cv = __popc(sr1) << 2;
      int bp = cv > sm.l.rngm[i1p & 15];
      int bi = cv > sm.l.rngm[i1i & 15];
      ng_prod = fg ? bp : (1 - bi);
      i1p += fg; i1i += 1 - fg;
    }
    A4 = clampi(A4 + (xgn << 1) - 1024);           // off 512
    int inb = (A4 >= 2); A4 -= inb << 1;
    A5 = clampi(A5 + ((inb + ng_prod) << 1) - 1);  // off 0.5
    int ng = (A5 >= 2); A5 -= ng << 1;

    sr2 = ((sr2 >> 1) | ((unsigned)ng << 3)) & 0xFu;
    int fgi;
    {
      int cv = __popc(sr2) << 2;
      int bp = cv > sm.l.rngm[i2p & 15];
      int bi = cv > sm.l.rngm[i2i & 15];
      fgi = (1 - fg) ? bp : (1 - bi);              // in0 = 1-fg
      i2p += 1 - fg; i2i += fg;
    }
    sr3 = ((sr3 >> 1) | ((unsigned)hcur << 3)) & 0xFu;
    int fgp;
    {
      int cv = __popc(sr3) << 2;
      int bp = cv > sm.l.rngm[i3p & 15];
      int bi = cv > sm.l.rngm[i3i & 15];
      fgp = fg ? bp : (1 - bi);                    // in0 = fg
      i3p += fg; i3i += 1 - fg;
    }
    A6 = clampi(A6 + ((ng + fgi + fgp) << 1) - 2); // off 1.0
    int hy = (A6 >= 2); A6 -= hy << 1;
    hcur = hy;

    if (t < 63){
      // publish: ballot low 32 bits = one chunk (lanes 0..31 hold outputs
      // 32w..32w+31; upper lanes are duplicates). Lane 0 of each wave stores.
      unsigned long long bal = __ballot(hy);
      if ((tid & 63) == 0){
        unsigned data = (unsigned)bal;
        unsigned long long val = (unsigned long long)data
                               | ((unsigned long long)(unsigned)(t + 1) << 32);
        __hip_atomic_store(
            &hw[(((size_t)((par ^ 1)*4 + bg))*64 + jt)*16 + (tid >> 6)], val,
            __ATOMIC_RELAXED, __HIP_MEMORY_SCOPE_AGENT);
      }
    }
    if (kh == 0)
      out[(size_t)t*131072 + (size_t)bglob*1024 + j0 + j_l] = (float)hy;
    if (t == 63) break;

    // commit prefetched t+1 tile into the OTHER mask buffer + xb
    {
      unsigned* mbuf = (unsigned*)sm.l.mask2[cur ^ 1];
      #pragma unroll
      for (int i = 0; i < 4; i++){
        int q = tid + i*NTHR;
        int r = q >> 6, qq = q & 63;
        mbuf[r*68 + qq] = mreg[i];
      }
      int bb = tid >> 5, w = tid & 31;
      sm.l.xb[bb*34 + w] = xreg;
    }
    __syncthreads();   // B1: t+1 masks/x visible; all h-popc(t) reads done

    // x-popc for t+1 (uses dreg = D'(t+1), loaded last iteration)
    {
      int s0=0, s1b=0;
      const uint2* xrow = (const uint2*)&sm.l.xb[b_l*34];
      const ulonglong2* m0p = (const ulonglong2*)&sm.l.mask2[cur ^ 1][(0  + j_l)*34];
      const ulonglong2* m1p = (const ulonglong2*)&sm.l.mask2[cur ^ 1][(16 + j_l)*34];
      #pragma unroll
      for (int w2i = 0; w2i < 8; w2i++){
        int w2 = w2lo + w2i;
        uint2 xv = xrow[w2];
        ulonglong2 a = m0p[w2];
        s0 += __popc(bfi(xv.x, (unsigned)a.x, (unsigned)(a.x >> 32)));
        s0 += __popc(bfi(xv.y, (unsigned)a.y, (unsigned)(a.y >> 32)));
        ulonglong2 b = m1p[w2];
        s1b += __popc(bfi(xv.x, (unsigned)b.x, (unsigned)(b.x >> 32)));
        s1b += __popc(bfi(xv.y, (unsigned)b.y, (unsigned)(b.y >> 32)));
      }
      s0 += __shfl_xor(s0, 32);
      s1b += __shfl_xor(s1b, 32);
      xgf = dreg[0] + s0;
      xgn = dreg[1] + s1b;
      dhf = dreg[2]; dhn = dreg[3];
    }

    // issue prefetch for tile t+2 (completes under the h wait)
    if (t < 62){
      #pragma unroll
      for (int i = 0; i < 4; i++){
        int q = tid + i*NTHR;
        int r = q >> 6, qq = q & 63;
        int c = (r >> 4)*1024 + j0 + (r & 15);
        mreg[i] = msrc[((size_t)(t+2)*4096 + c)*64 + qq];
      }
      {
        int bb = tid >> 5, w = tid & 31;
        xreg = xp[((size_t)(t+2)*128 + b0 + bb)*32 + w];
      }
      #pragma unroll
      for (int g = 0; g < 4; g++)
        dreg[g] = Dt[(t+2)*4096 + g*1024 + j0 + j_l];
    }

    // pull h(t+1): one tagged slot per thread, tag-spin
    {
      const unsigned ep = (unsigned)(t + 1);
      const unsigned long long* slot =
          &hw[((size_t)((par ^ 1)*4 + bg))*1024 + tid];
      unsigned long long v = __hip_atomic_load(slot, __ATOMIC_RELAXED,
                                               __HIP_MEMORY_SCOPE_AGENT);
      while ((unsigned)(v >> 32) < ep){
        __builtin_amdgcn_s_sleep(1);
        v = __hip_atomic_load(slot, __ATOMIC_RELAXED,
                              __HIP_MEMORY_SCOPE_AGENT);
      }
      int jt_ = tid >> 4, rp_ = tid & 15;
      unsigned data = (unsigned)v;
      sm.l.hrow16[(2*rp_)*68 + jt_]   = (unsigned short)(data & 0xFFFFu);
      sm.l.hrow16[(2*rp_+1)*68 + jt_] = (unsigned short)(data >> 16);
    }
    __syncthreads();   // B2: fresh h in LDS
    cur ^= 1;
  }
}

extern "C" void kernel_launch(void* const* d_in, const int* in_sizes, int n_in,
                              void* d_out, int out_size, void* d_ws, size_t ws_size,
                              hipStream_t stream)
{
  (void)in_sizes; (void)n_in; (void)out_size; (void)ws_size;
  const float* x   = (const float*)d_in[0];
  const float* hx0 = (const float*)d_in[1];
  const float* wih = (const float*)d_in[2];
  const float* bih = (const float*)d_in[3];
  const float* whh = (const float*)d_in[4];
  const float* bhh = (const float*)d_in[5];
  float* out = (float*)d_out;
  unsigned char* ws = (unsigned char*)d_ws;

  // reset setup-barrier lines + tagged h-slot region every call (replay-safe:
  // stale/poisoned tags must never satisfy a poll)
  hipMemsetAsync(d_ws, 0, 4096, stream);
  hipMemsetAsync(ws + WS_HW, 0, 65536, stream);

  void* args[] = { (void*)&x, (void*)&hx0, (void*)&wih, (void*)&bih,
                   (void*)&whh, (void*)&bhh, (void*)&out, (void*)&ws };
  hipLaunchCooperativeKernel(reinterpret_cast<void*>(fsu_kernel),
                             dim3(NBLK), dim3(NTHR), args, 0, stream);
}